// Round 3
// baseline (502.593 us; speedup 1.0000x reference)
//
#include <hip/hip_runtime.h>
#include <stdint.h>

typedef __attribute__((ext_vector_type(8))) short bf16x8;
typedef __attribute__((ext_vector_type(4))) float f32x4;

#define NSP 65536

// workspace byte offsets
#define WS_XN     0ULL         // 33554432  bf16 xnT swizzled [n][c]
#define WS_WFRAG  33554432ULL  // 524288    Wkv fragment buffer
#define WS_WEFRAG 34078720ULL  // 131072    Weff fragment buffer
#define WS_PART   34209792ULL  // 2048      stats partials -> later reduced sumexp[512]
#define WS_AB     34211840ULL  // 2048      per-channel a,b
#define WS_CTX    34215936ULL  // 131072    ctx[8][64][64]
#define WS_W2     34347008ULL  // 1048576   W2[256][512]
#define WS_WEFF   35395584ULL  // 262144    Weff[256][256]
#define WS_BEFF   35657728ULL  // 1024      beff[256]

// d_out doubles as partial-scratch before k_final overwrites it:
//   ctxp (bf16) = d_out[0 .. 32MB)        512 blocks * 32768 ushort
//   sump (f32)  = d_out[32MB .. 33MB)     512 blocks * 512 float, layout [block][r]
// total 33 MB < 64 MB of d_out.

__device__ __forceinline__ unsigned short f2bf(float f) {
  union { float f; uint32_t u; } v; v.f = f;
  uint32_t r = v.u + 0x7FFFu + ((v.u >> 16) & 1u);
  return (unsigned short)(r >> 16);
}
__device__ __forceinline__ float bf2f(unsigned short b) {
  union { uint32_t u; float f; } v; v.u = ((uint32_t)b) << 16;
  return v.f;
}

// ---------------- GroupNorm stats: 256 blocks, each 64KB chunk ----------------
__global__ void k_stats(const float* __restrict__ x, float* __restrict__ part) {
  __shared__ float ss[256], sq[256];
  const int t = threadIdx.x, b = blockIdx.x;
  const float4* p = (const float4*)(x + (size_t)b * 65536);
  float s = 0.f, qq = 0.f;
  for (int k = 0; k < 64; ++k) {
    float4 v = p[t + 256 * k];
    s  += v.x + v.y + v.z + v.w;
    qq += v.x * v.x + v.y * v.y + v.z * v.z + v.w * v.w;
  }
  ss[t] = s; sq[t] = qq;
  __syncthreads();
  for (int st = 128; st > 0; st >>= 1) {
    if (t < st) { ss[t] += ss[t + st]; sq[t] += sq[t + st]; }
    __syncthreads();
  }
  if (t == 0) { part[2 * b] = ss[0]; part[2 * b + 1] = sq[0]; }
}

// ---------------- per-channel a,b coefficients ----------------
__global__ void k_coef(const float* __restrict__ part, const float* __restrict__ gn_w,
                       const float* __restrict__ gn_b, float* __restrict__ ab) {
  const int c = threadIdx.x;
  const int g = c >> 3;
  float s = 0.f, q = 0.f;
  for (int j = 0; j < 8; ++j) { s += part[(g * 8 + j) * 2]; q += part[(g * 8 + j) * 2 + 1]; }
  const float inv = 1.0f / 524288.0f;
  const float mean = s * inv;
  const float var = q * inv - mean * mean;
  const float rstd = rsqrtf(var + 1e-5f);
  const float a = gn_w[c] * rstd;
  ab[c] = a;
  ab[256 + c] = gn_b[c] - mean * a;
}

// ---------------- normalize + cast + transpose + swizzle: xnT[n][c] bf16 ----------------
__global__ void k_xn(const float* __restrict__ x, const float* __restrict__ ab,
                     unsigned short* __restrict__ xn) {
  __shared__ float tile[64][68];
  const int t = threadIdx.x;
  const int nb = blockIdx.x, cb = blockIdx.y;
  {
    const int cl = t >> 2, nc = t & 3;
    const int c = cb * 64 + cl;
    const float a = ab[c], b = ab[256 + c];
    const float4* src = (const float4*)(x + (size_t)c * NSP + nb * 64 + nc * 16);
#pragma unroll
    for (int j = 0; j < 4; ++j) {
      float4 v = src[j];
      v.x = v.x * a + b; v.y = v.y * a + b; v.z = v.z * a + b; v.w = v.w * a + b;
      *(float4*)&tile[cl][nc * 16 + j * 4] = v;
    }
  }
  __syncthreads();
#pragma unroll
  for (int pass = 0; pass < 2; ++pass) {
    const int nl = pass * 32 + (t >> 3);
    const int ch = t & 7;
    const int u = ch ^ (nl & 7);      // XOR swizzle on 16B chunk index (bits 0-2)
    union { unsigned short s[8]; uint4 v; } pkv;
#pragma unroll
    for (int e = 0; e < 8; ++e) pkv.s[e] = f2bf(tile[u * 8 + e][nl]);
    *(uint4*)(xn + (size_t)(nb * 64 + nl) * 256 + cb * 64 + ch * 8) = pkv.v;
  }
}

// ---------------- pre-permute Wkv rows into MFMA B-fragment order ----------------
__global__ void k_wfrag(const float* __restrict__ qkv_w, unsigned short* __restrict__ wf) {
  const int blk = blockIdx.x;                 // blk = ks*64 + cf   (512 blocks)
  const int l = threadIdx.x;                  // 64
  const int row = 512 + (blk & 63) * 16 + (l & 15);
  const int c0 = (blk >> 6) * 32 + (l >> 4) * 8;
  const float* src = qkv_w + (size_t)row * 256 + c0;
  union { unsigned short s[8]; uint4 v; } u;
#pragma unroll
  for (int j = 0; j < 8; ++j) u.s[j] = f2bf(src[j]);
  *(uint4*)(wf + ((size_t)blk * 64 + l) * 8) = u.v;
}

// ---------------- fused KV-GEMM + exp + in-register context (no atomics) ----------------
__launch_bounds__(512, 2)
__global__ void k_kvctx(const unsigned short* __restrict__ xn,
                        const unsigned short* __restrict__ wfrag,
                        const float* __restrict__ qkv_b,
                        float* __restrict__ sump, unsigned short* __restrict__ ctxp) {
  __shared__ unsigned short xlds[16384];      // 64 n-rows * 512B (swizzled)
  const int t = threadIdx.x;
  const int w = t >> 6;                       // wave = head
  const int l = t & 63;
  const int q = l & 15, g = l >> 4;
  const f32x4 fz = {0.f, 0.f, 0.f, 0.f};

  f32x4 ctxa[4][4];
#pragma unroll
  for (int a = 0; a < 4; ++a)
#pragma unroll
    for (int b = 0; b < 4; ++b) ctxa[a][b] = fz;
  float srow[4] = {0.f, 0.f, 0.f, 0.f};
  float bk[4], bv[4];
#pragma unroll
  for (int jj = 0; jj < 4; ++jj) {
    bk[jj] = qkv_b[512 + w * 64 + jj * 16 + q];
    bv[jj] = qkv_b[1024 + w * 64 + jj * 16 + q];
  }

  for (int tt = 0; tt < 2; ++tt) {
    const size_t n0 = (size_t)blockIdx.x * 128 + tt * 64;
    __syncthreads();
    {
      const uint4* gs = (const uint4*)(xn + n0 * 256);
      uint4* ld = (uint4*)xlds;
#pragma unroll
      for (int k2 = 0; k2 < 4; ++k2) ld[t + 512 * k2] = gs[t + 512 * k2];
    }
    __syncthreads();

    f32x4 acc[4][4];
#pragma unroll
    for (int a = 0; a < 4; ++a)
#pragma unroll
      for (int b = 0; b < 4; ++b) acc[a][b] = fz;

    // K phase: kT tile = xnT @ WkT
#pragma unroll
    for (int ks = 0; ks < 8; ++ks) {
      bf16x8 xa[4];
#pragma unroll
      for (int i = 0; i < 4; ++i) {
        const int nl = i * 16 + q;
        const int boff = nl * 512 + ((ks * 64 + g * 16) ^ ((nl & 7) << 4));
        xa[i] = *(const bf16x8*)((const char*)xlds + boff);
      }
#pragma unroll
      for (int jj = 0; jj < 4; ++jj) {
        const bf16x8 bw = *(const bf16x8*)(wfrag + (((size_t)(ks * 64 + w * 4 + jj)) * 64 + l) * 8);
#pragma unroll
        for (int i = 0; i < 4; ++i)
          acc[i][jj] = __builtin_amdgcn_mfma_f32_16x16x32_bf16(xa[i], bw, acc[i][jj], 0, 0, 0);
      }
    }

    // bias + exp + pack to context-A fragments + row sums
    bf16x8 pk[4][2];
#pragma unroll
    for (int jj = 0; jj < 4; ++jj) {
      float s = 0.f;
#pragma unroll
      for (int i0 = 0; i0 < 2; ++i0) {
        bf16x8 p;
#pragma unroll
        for (int r = 0; r < 4; ++r) {
          const unsigned short u0 = f2bf(__expf(acc[2 * i0][jj][r] + bk[jj]));
          const unsigned short u1 = f2bf(__expf(acc[2 * i0 + 1][jj][r] + bk[jj]));
          p[r] = (short)u0; p[r + 4] = (short)u1;
          s += bf2f(u0) + bf2f(u1);
        }
        pk[jj][i0] = p;
      }
      srow[jj] += s;
    }

    // V phase
#pragma unroll
    for (int a = 0; a < 4; ++a)
#pragma unroll
      for (int b = 0; b < 4; ++b) acc[a][b] = fz;
#pragma unroll
    for (int ks = 0; ks < 8; ++ks) {
      bf16x8 xa[4];
#pragma unroll
      for (int i = 0; i < 4; ++i) {
        const int nl = i * 16 + q;
        const int boff = nl * 512 + ((ks * 64 + g * 16) ^ ((nl & 7) << 4));
        xa[i] = *(const bf16x8*)((const char*)xlds + boff);
      }
#pragma unroll
      for (int jj = 0; jj < 4; ++jj) {
        const bf16x8 bw = *(const bf16x8*)(wfrag + (((size_t)(ks * 64 + 32 + w * 4 + jj)) * 64 + l) * 8);
#pragma unroll
        for (int i = 0; i < 4; ++i)
          acc[i][jj] = __builtin_amdgcn_mfma_f32_16x16x32_bf16(xa[i], bw, acc[i][jj], 0, 0, 0);
      }
    }
    bf16x8 pv[4][2];
#pragma unroll
    for (int jj = 0; jj < 4; ++jj) {
#pragma unroll
      for (int i0 = 0; i0 < 2; ++i0) {
        bf16x8 p;
#pragma unroll
        for (int r = 0; r < 4; ++r) {
          p[r]     = (short)f2bf(acc[2 * i0][jj][r] + bv[jj]);
          p[r + 4] = (short)f2bf(acc[2 * i0 + 1][jj][r] + bv[jj]);
        }
        pv[jj][i0] = p;
      }
    }

    // context: ctx[d,e] += exp(k)[d,n] * v[e,n]  (all in-register)
#pragma unroll
    for (int i0 = 0; i0 < 2; ++i0)
#pragma unroll
      for (int ja = 0; ja < 4; ++ja)
#pragma unroll
        for (int jb = 0; jb < 4; ++jb)
          ctxa[ja][jb] = __builtin_amdgcn_mfma_f32_16x16x32_bf16(pk[ja][i0], pv[jb][i0], ctxa[ja][jb], 0, 0, 0);
  }

  // emit per-block partials (plain stores, no atomics)
#pragma unroll
  for (int jj = 0; jj < 4; ++jj) {
    float s = srow[jj];
    s += __shfl_xor(s, 16, 64);
    s += __shfl_xor(s, 32, 64);
    if (l < 16) sump[(size_t)blockIdx.x * 512 + w * 64 + jj * 16 + q] = s;
  }
  unsigned short* cp = ctxp + (size_t)blockIdx.x * 32768 + (size_t)w * 4096;
#pragma unroll
  for (int ja = 0; ja < 4; ++ja)
#pragma unroll
    for (int jb = 0; jb < 4; ++jb)
#pragma unroll
      for (int r = 0; r < 4; ++r)
        cp[(size_t)(ja * 16 + g * 4 + r) * 64 + jb * 16 + q] = f2bf(ctxa[ja][jb][r]);
}

// ---------------- reduce partials: ctx (blocks 0..255), sumexp (blocks 256..259) ----------------
__global__ void k_ctxred(const unsigned short* __restrict__ ctxp, const float* __restrict__ sump,
                         float* __restrict__ ctx, float* __restrict__ sexp) {
  const int t = threadIdx.x;
  if (blockIdx.x < 256) {
    const int idx = blockIdx.x * 128 + t;
    const unsigned short* p = ctxp + idx;
    float s = 0.f;
#pragma unroll 8
    for (int b = 0; b < 512; ++b) s += bf2f(p[(size_t)b * 32768]);
    ctx[idx] = s;
  } else {
    const int r = (blockIdx.x - 256) * 128 + t;
    float s = 0.f;
#pragma unroll 8
    for (int b = 0; b < 512; ++b) s += sump[(size_t)b * 512 + r];
    sexp[r] = s;
  }
}

// ---------------- W2[o][r] = sum_e out_w[o][h*64+e] * ctx[h][d][e] / sumexp[r] ----------------
__global__ void k_w2(const float* __restrict__ out_w, const float* __restrict__ ctx,
                     const float* __restrict__ sexp, float* __restrict__ w2) {
  const int r = blockIdx.x;            // 512
  const int h = r >> 6, d = r & 63;
  __shared__ float row[64];
  __shared__ float sinv;
  const int t = threadIdx.x;
  if (t < 64) row[t] = ctx[((size_t)h * 64 + d) * 64 + t];
  if (t == 0) sinv = 1.0f / sexp[r];
  __syncthreads();
  float a = 0.f;
  const float* wp = out_w + (size_t)t * 512 + h * 64;
#pragma unroll 8
  for (int e = 0; e < 64; ++e) a += wp[e] * row[e];
  w2[(size_t)t * 512 + r] = a * sinv;
}

// ---------------- Weff = W2 @ Wq ----------------
__global__ void k_weff(const float* __restrict__ w2, const float* __restrict__ qkv_w,
                       float* __restrict__ weff) {
  const int o = blockIdx.x;            // 256
  const int c = threadIdx.x;           // 256
  __shared__ float row[512];
  row[c] = w2[(size_t)o * 512 + c];
  row[256 + c] = w2[(size_t)o * 512 + 256 + c];
  __syncthreads();
  float a = 0.f;
#pragma unroll 8
  for (int r = 0; r < 512; ++r) a += row[r] * qkv_w[(size_t)r * 256 + c];
  weff[o * 256 + c] = a;
}

// ---------------- permute Weff into MFMA B-fragment order ----------------
__global__ void k_wefrag(const float* __restrict__ weff, unsigned short* __restrict__ wf) {
  const int blk = blockIdx.x;          // blk = ks*16 + cf   (128 blocks)
  const int l = threadIdx.x;           // 64
  const int row = (blk & 15) * 16 + (l & 15);
  const int c0 = (blk >> 4) * 32 + (l >> 4) * 8;
  const float* src = weff + (size_t)row * 256 + c0;
  union { unsigned short s[8]; uint4 v; } u;
#pragma unroll
  for (int j = 0; j < 8; ++j) u.s[j] = f2bf(src[j]);
  *(uint4*)(wf + ((size_t)blk * 64 + l) * 8) = u.v;
}

// ---------------- beff = out_b + W2 @ bq ----------------
__global__ void k_beff(const float* __restrict__ w2, const float* __restrict__ qkv_b,
                       const float* __restrict__ out_b, float* __restrict__ beff) {
  const int o = threadIdx.x;
  float a = out_b[o];
#pragma unroll 8
  for (int r = 0; r < 512; ++r) a += w2[(size_t)o * 512 + r] * qkv_b[r];
  beff[o] = a;
}

// ---------------- final: out = Weff @ xn + beff ----------------
__launch_bounds__(256, 2)
__global__ void k_final(const unsigned short* __restrict__ xn,
                        const unsigned short* __restrict__ wef,
                        const float* __restrict__ beff,
                        float* __restrict__ out) {
  __shared__ unsigned short xlds[32768];   // 128 n-rows * 512B (swizzled)
  const int t = threadIdx.x;
  const int w = t >> 6, l = t & 63;
  const int q = l & 15, g = l >> 4;
  const int si = w >> 1, sj = w & 1;
  const size_t n0 = (size_t)blockIdx.x * 128;
  {
    const uint4* gs = (const uint4*)(xn + n0 * 256);
    uint4* ld = (uint4*)xlds;
#pragma unroll
    for (int k2 = 0; k2 < 16; ++k2) ld[t + 256 * k2] = gs[t + 256 * k2];
  }
  __syncthreads();
  const f32x4 fz = {0.f, 0.f, 0.f, 0.f};
  f32x4 acc[4][8];
#pragma unroll
  for (int i = 0; i < 4; ++i)
#pragma unroll
    for (int j = 0; j < 8; ++j) acc[i][j] = fz;
#pragma unroll
  for (int ks = 0; ks < 8; ++ks) {
    bf16x8 xa[4];
#pragma unroll
    for (int i = 0; i < 4; ++i) {
      const int nl = si * 64 + i * 16 + q;
      const int boff = nl * 512 + ((ks * 64 + g * 16) ^ ((nl & 7) << 4));
      xa[i] = *(const bf16x8*)((const char*)xlds + boff);
    }
#pragma unroll
    for (int jj = 0; jj < 8; ++jj) {
      const bf16x8 bw = *(const bf16x8*)(wef + (((size_t)(ks * 16 + sj * 8 + jj)) * 64 + l) * 8);
#pragma unroll
      for (int i = 0; i < 4; ++i)
        acc[i][jj] = __builtin_amdgcn_mfma_f32_16x16x32_bf16(xa[i], bw, acc[i][jj], 0, 0, 0);
    }
  }
#pragma unroll
  for (int jj = 0; jj < 8; ++jj) {
    const int o = sj * 128 + jj * 16 + q;
    const float be = beff[o];
#pragma unroll
    for (int i = 0; i < 4; ++i) {
      const size_t nn = n0 + si * 64 + i * 16 + g * 4;
      float4 v;
      v.x = acc[i][jj][0] + be; v.y = acc[i][jj][1] + be;
      v.z = acc[i][jj][2] + be; v.w = acc[i][jj][3] + be;
      *(float4*)(out + (size_t)o * NSP + nn) = v;
    }
  }
}

extern "C" void kernel_launch(void* const* d_in, const int* in_sizes, int n_in,
                              void* d_out, int out_size, void* d_ws, size_t ws_size,
                              hipStream_t stream) {
  const float* x     = (const float*)d_in[0];
  const float* gn_w  = (const float*)d_in[1];
  const float* gn_b  = (const float*)d_in[2];
  const float* qkv_w = (const float*)d_in[3];
  const float* qkv_b = (const float*)d_in[4];
  const float* out_w = (const float*)d_in[5];
  const float* out_b = (const float*)d_in[6];
  char* ws = (char*)d_ws;
  unsigned short* xn  = (unsigned short*)(ws + WS_XN);
  unsigned short* wf  = (unsigned short*)(ws + WS_WFRAG);
  unsigned short* wef = (unsigned short*)(ws + WS_WEFRAG);
  float* part   = (float*)(ws + WS_PART);   // stats partials, then reduced sumexp
  float* ab     = (float*)(ws + WS_AB);
  float* ctx    = (float*)(ws + WS_CTX);
  float* w2     = (float*)(ws + WS_W2);
  float* weff   = (float*)(ws + WS_WEFF);
  float* beff   = (float*)(ws + WS_BEFF);
  float* out    = (float*)d_out;
  // d_out doubles as partial scratch (fully overwritten by k_final):
  unsigned short* ctxp = (unsigned short*)d_out;            // 512*32768 bf16 = 32 MB
  float* sump = (float*)((char*)d_out + 33554432ULL);       // 512*512 f32 = 1 MB (33 MB < 64 MB)

  k_wfrag<<<512, 64, 0, stream>>>(qkv_w, wf);
  k_stats<<<256, 256, 0, stream>>>(x, part);
  k_coef<<<1, 256, 0, stream>>>(part, gn_w, gn_b, ab);
  k_xn<<<dim3(1024, 4), 256, 0, stream>>>(x, ab, xn);
  k_kvctx<<<512, 512, 0, stream>>>(xn, wf, qkv_b, sump, ctxp);
  k_ctxred<<<260, 128, 0, stream>>>(ctxp, sump, ctx, part);
  k_w2<<<512, 256, 0, stream>>>(out_w, ctx, part, w2);
  k_weff<<<256, 256, 0, stream>>>(w2, qkv_w, weff);
  k_wefrag<<<128, 64, 0, stream>>>(weff, wef);
  k_beff<<<1, 256, 0, stream>>>(w2, qkv_b, out_b, beff);
  k_final<<<512, 256, 0, stream>>>(xn, wef, beff, out);
}

// Round 5
// 425.069 us; speedup vs baseline: 1.1824x; 1.1824x over previous
//
#include <hip/hip_runtime.h>
#include <stdint.h>

typedef __attribute__((ext_vector_type(8))) short bf16x8;
typedef __attribute__((ext_vector_type(4))) float f32x4;
typedef __attribute__((ext_vector_type(4))) unsigned int u32x4;
typedef __attribute__((ext_vector_type(2))) unsigned int u32x2;

#define NSP 65536

// workspace byte offsets
#define WS_XN     0ULL         // 33554432  bf16 xnT swizzled [n][c]
#define WS_WFRAG  33554432ULL  // 524288    Wkv fragment buffer
#define WS_WEFRAG 34078720ULL  // 131072    Weff fragment buffer
#define WS_PART   34209792ULL  // 2048      stats partials -> later reduced sumexp[512]
#define WS_AB     34211840ULL  // 2048      per-channel a,b
#define WS_CTX    34215936ULL  // 131072    ctx[8][64][64]
#define WS_W2     34347008ULL  // 1048576   W2[256][512]
#define WS_WEFF   35395584ULL  // 262144    Weff[256][256]
#define WS_BEFF   35657728ULL  // 1024      beff[256]

// d_out doubles as partial-scratch before k_final overwrites it:
//   ctxp (bf16) = d_out[0 .. 32MB)     512 blocks * 8192 u32x2 (fragment-natural layout)
//   sump (f32)  = d_out[32MB .. 33MB)  512 blocks * 512 float, layout [block][r]

__device__ __forceinline__ unsigned short f2bf(float f) {
  union { float f; uint32_t u; } v; v.f = f;
  uint32_t r = v.u + 0x7FFFu + ((v.u >> 16) & 1u);
  return (unsigned short)(r >> 16);
}
__device__ __forceinline__ float bf2f(unsigned short b) {
  union { uint32_t u; float f; } v; v.u = ((uint32_t)b) << 16;
  return v.f;
}

// ---------------- GroupNorm stats: 256 blocks, each 64KB chunk ----------------
__global__ void k_stats(const float* __restrict__ x, float* __restrict__ part) {
  __shared__ float ss[256], sq[256];
  const int t = threadIdx.x, b = blockIdx.x;
  const f32x4* p = (const f32x4*)(x + (size_t)b * 65536);
  float s = 0.f, qq = 0.f;
  for (int k = 0; k < 64; ++k) {
    f32x4 v = __builtin_nontemporal_load(p + t + 256 * k);
    s  += v[0] + v[1] + v[2] + v[3];
    qq += v[0] * v[0] + v[1] * v[1] + v[2] * v[2] + v[3] * v[3];
  }
  ss[t] = s; sq[t] = qq;
  __syncthreads();
  for (int st = 128; st > 0; st >>= 1) {
    if (t < st) { ss[t] += ss[t + st]; sq[t] += sq[t + st]; }
    __syncthreads();
  }
  if (t == 0) { part[2 * b] = ss[0]; part[2 * b + 1] = sq[0]; }
}

// ---------------- per-channel a,b coefficients ----------------
__global__ void k_coef(const float* __restrict__ part, const float* __restrict__ gn_w,
                       const float* __restrict__ gn_b, float* __restrict__ ab) {
  const int c = threadIdx.x;
  const int g = c >> 3;
  float s = 0.f, q = 0.f;
  for (int j = 0; j < 8; ++j) { s += part[(g * 8 + j) * 2]; q += part[(g * 8 + j) * 2 + 1]; }
  const float inv = 1.0f / 524288.0f;
  const float mean = s * inv;
  const float var = q * inv - mean * mean;
  const float rstd = rsqrtf(var + 1e-5f);
  const float a = gn_w[c] * rstd;
  ab[c] = a;
  ab[256 + c] = gn_b[c] - mean * a;
}

// ---------------- normalize + cast + transpose + swizzle: xnT[n][c] bf16 ----------------
__global__ void k_xn(const float* __restrict__ x, const float* __restrict__ ab,
                     unsigned short* __restrict__ xn) {
  __shared__ float tile[64][68];
  const int t = threadIdx.x;
  const int nb = blockIdx.x, cb = blockIdx.y;
  {
    const int cl = t >> 2, nc = t & 3;
    const int c = cb * 64 + cl;
    const float a = ab[c], b = ab[256 + c];
    const f32x4* src = (const f32x4*)(x + (size_t)c * NSP + nb * 64 + nc * 16);
#pragma unroll
    for (int j = 0; j < 4; ++j) {
      f32x4 v = __builtin_nontemporal_load(src + j);
      v = v * a + b;
      *(f32x4*)&tile[cl][nc * 16 + j * 4] = v;
    }
  }
  __syncthreads();
#pragma unroll
  for (int pass = 0; pass < 2; ++pass) {
    const int nl = pass * 32 + (t >> 3);
    const int ch = t & 7;
    const int u = ch ^ (nl & 7);      // XOR swizzle on 16B chunk index (bits 0-2)
    union { unsigned short s[8]; u32x4 v; } pkv;
#pragma unroll
    for (int e = 0; e < 8; ++e) pkv.s[e] = f2bf(tile[u * 8 + e][nl]);
    __builtin_nontemporal_store(pkv.v, (u32x4*)(xn + (size_t)(nb * 64 + nl) * 256 + cb * 64 + ch * 8));
  }
}

// ---------------- pre-permute Wkv rows into MFMA B-fragment order ----------------
__global__ void k_wfrag(const float* __restrict__ qkv_w, unsigned short* __restrict__ wf) {
  const int blk = blockIdx.x;                 // blk = ks*64 + cf   (512 blocks)
  const int l = threadIdx.x;                  // 64
  const int row = 512 + (blk & 63) * 16 + (l & 15);
  const int c0 = (blk >> 6) * 32 + (l >> 4) * 8;
  const float* src = qkv_w + (size_t)row * 256 + c0;
  union { unsigned short s[8]; u32x4 v; } u;
#pragma unroll
  for (int j = 0; j < 8; ++j) u.s[j] = f2bf(src[j]);
  *(u32x4*)(wf + ((size_t)blk * 64 + l) * 8) = u.v;
}

// ---------------- fused KV-GEMM + exp + in-register context (no atomics) ----------------
__launch_bounds__(512, 2)
__global__ void k_kvctx(const unsigned short* __restrict__ xn,
                        const unsigned short* __restrict__ wfrag,
                        const float* __restrict__ qkv_b,
                        float* __restrict__ sump, u32x2* __restrict__ ctxp) {
  __shared__ unsigned short xlds[16384];      // 64 n-rows * 512B (swizzled)
  const int t = threadIdx.x;
  const int w = t >> 6;                       // wave = head
  const int l = t & 63;
  const int q = l & 15, g = l >> 4;
  const f32x4 fz = {0.f, 0.f, 0.f, 0.f};

  f32x4 ctxa[4][4];
#pragma unroll
  for (int a = 0; a < 4; ++a)
#pragma unroll
    for (int b = 0; b < 4; ++b) ctxa[a][b] = fz;
  float srow[4] = {0.f, 0.f, 0.f, 0.f};
  float bk[4], bv[4];
#pragma unroll
  for (int jj = 0; jj < 4; ++jj) {
    bk[jj] = qkv_b[512 + w * 64 + jj * 16 + q];
    bv[jj] = qkv_b[1024 + w * 64 + jj * 16 + q];
  }

  for (int tt = 0; tt < 2; ++tt) {
    const size_t n0 = (size_t)blockIdx.x * 128 + tt * 64;
    __syncthreads();
    {
      const u32x4* gs = (const u32x4*)(xn + n0 * 256);
      u32x4* ld = (u32x4*)xlds;
#pragma unroll
      for (int k2 = 0; k2 < 4; ++k2) {
        u32x4 v = __builtin_nontemporal_load(gs + t + 512 * k2);
        ld[t + 512 * k2] = v;
      }
    }
    __syncthreads();

    f32x4 acc[4][4];
#pragma unroll
    for (int a = 0; a < 4; ++a)
#pragma unroll
      for (int b = 0; b < 4; ++b) acc[a][b] = fz;

    // K phase: kT tile = xnT @ WkT
#pragma unroll
    for (int ks = 0; ks < 8; ++ks) {
      bf16x8 xa[4];
#pragma unroll
      for (int i = 0; i < 4; ++i) {
        const int nl = i * 16 + q;
        const int boff = nl * 512 + ((ks * 64 + g * 16) ^ ((nl & 7) << 4));
        xa[i] = *(const bf16x8*)((const char*)xlds + boff);
      }
#pragma unroll
      for (int jj = 0; jj < 4; ++jj) {
        const bf16x8 bw = *(const bf16x8*)(wfrag + (((size_t)(ks * 64 + w * 4 + jj)) * 64 + l) * 8);
#pragma unroll
        for (int i = 0; i < 4; ++i)
          acc[i][jj] = __builtin_amdgcn_mfma_f32_16x16x32_bf16(xa[i], bw, acc[i][jj], 0, 0, 0);
      }
    }

    // bias + exp + pack to context-A fragments + row sums
    bf16x8 pk[4][2];
#pragma unroll
    for (int jj = 0; jj < 4; ++jj) {
      float s = 0.f;
#pragma unroll
      for (int i0 = 0; i0 < 2; ++i0) {
        bf16x8 p;
#pragma unroll
        for (int r = 0; r < 4; ++r) {
          const unsigned short u0 = f2bf(__expf(acc[2 * i0][jj][r] + bk[jj]));
          const unsigned short u1 = f2bf(__expf(acc[2 * i0 + 1][jj][r] + bk[jj]));
          p[r] = (short)u0; p[r + 4] = (short)u1;
          s += bf2f(u0) + bf2f(u1);
        }
        pk[jj][i0] = p;
      }
      srow[jj] += s;
    }

    // V phase
#pragma unroll
    for (int a = 0; a < 4; ++a)
#pragma unroll
      for (int b = 0; b < 4; ++b) acc[a][b] = fz;
#pragma unroll
    for (int ks = 0; ks < 8; ++ks) {
      bf16x8 xa[4];
#pragma unroll
      for (int i = 0; i < 4; ++i) {
        const int nl = i * 16 + q;
        const int boff = nl * 512 + ((ks * 64 + g * 16) ^ ((nl & 7) << 4));
        xa[i] = *(const bf16x8*)((const char*)xlds + boff);
      }
#pragma unroll
      for (int jj = 0; jj < 4; ++jj) {
        const bf16x8 bw = *(const bf16x8*)(wfrag + (((size_t)(ks * 64 + 32 + w * 4 + jj)) * 64 + l) * 8);
#pragma unroll
        for (int i = 0; i < 4; ++i)
          acc[i][jj] = __builtin_amdgcn_mfma_f32_16x16x32_bf16(xa[i], bw, acc[i][jj], 0, 0, 0);
      }
    }
    bf16x8 pv[4][2];
#pragma unroll
    for (int jj = 0; jj < 4; ++jj) {
#pragma unroll
      for (int i0 = 0; i0 < 2; ++i0) {
        bf16x8 p;
#pragma unroll
        for (int r = 0; r < 4; ++r) {
          p[r]     = (short)f2bf(acc[2 * i0][jj][r] + bv[jj]);
          p[r + 4] = (short)f2bf(acc[2 * i0 + 1][jj][r] + bv[jj]);
        }
        pv[jj][i0] = p;
      }
    }

    // context: ctx[d,e] += exp(k)[d,n] * v[e,n]  (all in-register)
#pragma unroll
    for (int i0 = 0; i0 < 2; ++i0)
#pragma unroll
      for (int ja = 0; ja < 4; ++ja)
#pragma unroll
        for (int jb = 0; jb < 4; ++jb)
          ctxa[ja][jb] = __builtin_amdgcn_mfma_f32_16x16x32_bf16(pk[ja][i0], pv[jb][i0], ctxa[ja][jb], 0, 0, 0);
  }

  // emit per-block partials: fragment-natural layout, fully coalesced 8B stores
#pragma unroll
  for (int jj = 0; jj < 4; ++jj) {
    float s = srow[jj];
    s += __shfl_xor(s, 16, 64);
    s += __shfl_xor(s, 32, 64);
    if (l < 16) __builtin_nontemporal_store(s, &sump[(size_t)blockIdx.x * 512 + w * 64 + jj * 16 + q]);
  }
  u32x2* cp2 = ctxp + (size_t)blockIdx.x * 8192 + w * 1024 + l;
#pragma unroll
  for (int ja = 0; ja < 4; ++ja)
#pragma unroll
    for (int jb = 0; jb < 4; ++jb) {
      union { unsigned short s[4]; u32x2 v; } u;
#pragma unroll
      for (int r = 0; r < 4; ++r) u.s[r] = f2bf(ctxa[ja][jb][r]);
      __builtin_nontemporal_store(u.v, cp2 + (ja * 4 + jb) * 64);
    }
}

// ---------------- reduce partials: ctx (blocks 0..63), sumexp (blocks 64..67) ----------------
__global__ void k_ctxred(const u32x2* __restrict__ ctxp, const float* __restrict__ sump,
                         float* __restrict__ ctx, float* __restrict__ sexp) {
  const int t = threadIdx.x;
  if (blockIdx.x < 64) {
    const int j = blockIdx.x * 128 + t;       // u32x2 index in [0, 8192)
    float s0 = 0.f, s1 = 0.f, s2 = 0.f, s3 = 0.f;
    const u32x2* p = ctxp + j;
    for (int b = 0; b < 512; ++b) {
      const u32x2 v = p[(size_t)b * 8192];
      s0 += bf2f((unsigned short)(v[0] & 0xFFFF));
      s1 += bf2f((unsigned short)(v[0] >> 16));
      s2 += bf2f((unsigned short)(v[1] & 0xFFFF));
      s3 += bf2f((unsigned short)(v[1] >> 16));
    }
    const int w = j >> 10, j2 = j & 1023;
    const int jajb = j2 >> 6, ja = jajb >> 2, jb = jajb & 3;
    const int l = j2 & 63, g = l >> 4, q = l & 15;
    float* cw = ctx + ((size_t)w * 64 + ja * 16 + g * 4) * 64 + jb * 16 + q;
    cw[0]   = s0;
    cw[64]  = s1;
    cw[128] = s2;
    cw[192] = s3;
  } else {
    const int r = (blockIdx.x - 64) * 128 + t;
    float s = 0.f;
#pragma unroll 8
    for (int b = 0; b < 512; ++b) s += sump[(size_t)b * 512 + r];
    sexp[r] = s;
  }
}

// ---------------- W2[o][r] = sum_e out_w[o][h*64+e] * ctx[h][d][e] / sumexp[r] ----------------
__global__ void k_w2(const float* __restrict__ out_w, const float* __restrict__ ctx,
                     const float* __restrict__ sexp, float* __restrict__ w2) {
  const int r = blockIdx.x;            // 512
  const int h = r >> 6, d = r & 63;
  __shared__ float row[64];
  __shared__ float sinv;
  const int t = threadIdx.x;
  if (t < 64) row[t] = ctx[((size_t)h * 64 + d) * 64 + t];
  if (t == 0) sinv = 1.0f / sexp[r];
  __syncthreads();
  float a = 0.f;
  const float* wp = out_w + (size_t)t * 512 + h * 64;
#pragma unroll 8
  for (int e = 0; e < 64; ++e) a += wp[e] * row[e];
  w2[(size_t)t * 512 + r] = a * sinv;
}

// ---------------- Weff = W2 @ Wq ----------------
__global__ void k_weff(const float* __restrict__ w2, const float* __restrict__ qkv_w,
                       float* __restrict__ weff) {
  const int o = blockIdx.x;            // 256
  const int c = threadIdx.x;           // 256
  __shared__ float row[512];
  row[c] = w2[(size_t)o * 512 + c];
  row[256 + c] = w2[(size_t)o * 512 + 256 + c];
  __syncthreads();
  float a = 0.f;
#pragma unroll 8
  for (int r = 0; r < 512; ++r) a += row[r] * qkv_w[(size_t)r * 256 + c];
  weff[o * 256 + c] = a;
}

// ---------------- permute Weff into MFMA B-fragment order ----------------
__global__ void k_wefrag(const float* __restrict__ weff, unsigned short* __restrict__ wf) {
  const int blk = blockIdx.x;          // blk = ks*16 + cf   (128 blocks)
  const int l = threadIdx.x;           // 64
  const int row = (blk & 15) * 16 + (l & 15);
  const int c0 = (blk >> 4) * 32 + (l >> 4) * 8;
  const float* src = weff + (size_t)row * 256 + c0;
  union { unsigned short s[8]; u32x4 v; } u;
#pragma unroll
  for (int j = 0; j < 8; ++j) u.s[j] = f2bf(src[j]);
  *(u32x4*)(wf + ((size_t)blk * 64 + l) * 8) = u.v;
}

// ---------------- beff = out_b + W2 @ bq ----------------
__global__ void k_beff(const float* __restrict__ w2, const float* __restrict__ qkv_b,
                       const float* __restrict__ out_b, float* __restrict__ beff) {
  const int o = threadIdx.x;
  float a = out_b[o];
#pragma unroll 8
  for (int r = 0; r < 512; ++r) a += w2[(size_t)o * 512 + r] * qkv_b[r];
  beff[o] = a;
}

// ---------------- final: out = Weff @ xn + beff ----------------
__launch_bounds__(256, 2)
__global__ void k_final(const unsigned short* __restrict__ xn,
                        const unsigned short* __restrict__ wef,
                        const float* __restrict__ beff,
                        float* __restrict__ out) {
  __shared__ unsigned short xlds[32768];   // 128 n-rows * 512B (swizzled)
  const int t = threadIdx.x;
  const int w = t >> 6, l = t & 63;
  const int q = l & 15, g = l >> 4;
  const int si = w >> 1, sj = w & 1;
  const size_t n0 = (size_t)blockIdx.x * 128;
  {
    const u32x4* gs = (const u32x4*)(xn + n0 * 256);
    u32x4* ld = (u32x4*)xlds;
#pragma unroll
    for (int k2 = 0; k2 < 16; ++k2) {
      u32x4 v = __builtin_nontemporal_load(gs + t + 256 * k2);
      ld[t + 256 * k2] = v;
    }
  }
  __syncthreads();
  const f32x4 fz = {0.f, 0.f, 0.f, 0.f};
  f32x4 acc[4][8];
#pragma unroll
  for (int i = 0; i < 4; ++i)
#pragma unroll
    for (int j = 0; j < 8; ++j) acc[i][j] = fz;
#pragma unroll
  for (int ks = 0; ks < 8; ++ks) {
    bf16x8 xa[4];
#pragma unroll
    for (int i = 0; i < 4; ++i) {
      const int nl = si * 64 + i * 16 + q;
      const int boff = nl * 512 + ((ks * 64 + g * 16) ^ ((nl & 7) << 4));
      xa[i] = *(const bf16x8*)((const char*)xlds + boff);
    }
#pragma unroll
    for (int jj = 0; jj < 8; ++jj) {
      const bf16x8 bw = *(const bf16x8*)(wef + (((size_t)(ks * 16 + sj * 8 + jj)) * 64 + l) * 8);
#pragma unroll
      for (int i = 0; i < 4; ++i)
        acc[i][jj] = __builtin_amdgcn_mfma_f32_16x16x32_bf16(xa[i], bw, acc[i][jj], 0, 0, 0);
    }
  }
#pragma unroll
  for (int jj = 0; jj < 8; ++jj) {
    const int o = sj * 128 + jj * 16 + q;
    const float be = beff[o];
#pragma unroll
    for (int i = 0; i < 4; ++i) {
      const size_t nn = n0 + si * 64 + i * 16 + g * 4;
      f32x4 v;
      v[0] = acc[i][jj][0] + be; v[1] = acc[i][jj][1] + be;
      v[2] = acc[i][jj][2] + be; v[3] = acc[i][jj][3] + be;
      __builtin_nontemporal_store(v, (f32x4*)(out + (size_t)o * NSP + nn));
    }
  }
}

extern "C" void kernel_launch(void* const* d_in, const int* in_sizes, int n_in,
                              void* d_out, int out_size, void* d_ws, size_t ws_size,
                              hipStream_t stream) {
  const float* x     = (const float*)d_in[0];
  const float* gn_w  = (const float*)d_in[1];
  const float* gn_b  = (const float*)d_in[2];
  const float* qkv_w = (const float*)d_in[3];
  const float* qkv_b = (const float*)d_in[4];
  const float* out_w = (const float*)d_in[5];
  const float* out_b = (const float*)d_in[6];
  char* ws = (char*)d_ws;
  unsigned short* xn  = (unsigned short*)(ws + WS_XN);
  unsigned short* wf  = (unsigned short*)(ws + WS_WFRAG);
  unsigned short* wef = (unsigned short*)(ws + WS_WEFRAG);
  float* part   = (float*)(ws + WS_PART);   // stats partials, then reduced sumexp
  float* ab     = (float*)(ws + WS_AB);
  float* ctx    = (float*)(ws + WS_CTX);
  float* w2     = (float*)(ws + WS_W2);
  float* weff   = (float*)(ws + WS_WEFF);
  float* beff   = (float*)(ws + WS_BEFF);
  float* out    = (float*)d_out;
  // d_out doubles as partial scratch (fully overwritten by k_final):
  u32x2* ctxp = (u32x2*)d_out;                              // 512*8192 u32x2 = 32 MB
  float* sump = (float*)((char*)d_out + 33554432ULL);       // 512*512 f32 = 1 MB

  k_wfrag<<<512, 64, 0, stream>>>(qkv_w, wf);
  k_stats<<<256, 256, 0, stream>>>(x, part);
  k_coef<<<1, 256, 0, stream>>>(part, gn_w, gn_b, ab);
  k_xn<<<dim3(1024, 4), 256, 0, stream>>>(x, ab, xn);
  k_kvctx<<<512, 512, 0, stream>>>(xn, wf, qkv_b, sump, ctxp);
  k_ctxred<<<68, 128, 0, stream>>>(ctxp, sump, ctx, part);
  k_w2<<<512, 256, 0, stream>>>(out_w, ctx, part, w2);
  k_weff<<<256, 256, 0, stream>>>(w2, qkv_w, weff);
  k_wefrag<<<128, 64, 0, stream>>>(weff, wef);
  k_beff<<<1, 256, 0, stream>>>(w2, qkv_b, out_b, beff);
  k_final<<<512, 256, 0, stream>>>(xn, wef, beff, out);
}

// Round 6
// 409.902 us; speedup vs baseline: 1.2261x; 1.0370x over previous
//
#include <hip/hip_runtime.h>
#include <stdint.h>

typedef __attribute__((ext_vector_type(8))) short bf16x8;
typedef __attribute__((ext_vector_type(4))) float f32x4;
typedef __attribute__((ext_vector_type(4))) unsigned int u32x4;

#define NSP 65536

// workspace byte offsets
#define WS_XN     0ULL         // 33554432  bf16 xnT swizzled [n][c]   (k_final)
#define WS_WFRAG  33554432ULL  // 524288    Wkv fragment buffer
#define WS_WEFRAG 34078720ULL  // 131072    Weff fragment buffer
#define WS_PART   34209792ULL  // 2048      stats partials -> reduced sumexp[512]
#define WS_AB     34211840ULL  // 2048      per-channel a,b
#define WS_CTX    34215936ULL  // 131072    ctx[8][64][64]
#define WS_W2     34347008ULL  // 1048576   W2[256][512]
#define WS_WEFF   35395584ULL  // 262144    Weff[256][256]
#define WS_BEFF   35657728ULL  // 1024      beff[256]

// d_out doubles as scratch before k_final overwrites it:
//   xnf  (bf16) [0 .. 32MB)       fragment-native xn for k_kvctx
//   ctxp (f32)  [32MB .. 40MB)    8 heads * 64 chunks * 4096 partials
//   sump (f32)  [40MB .. +128KB)  [h*64+d][chunk]

__device__ __forceinline__ unsigned short f2bf(float f) {
  union { float f; uint32_t u; } v; v.f = f;
  uint32_t r = v.u + 0x7FFFu + ((v.u >> 16) & 1u);
  return (unsigned short)(r >> 16);
}
__device__ __forceinline__ float bf2f(unsigned short b) {
  union { uint32_t u; float f; } v; v.u = ((uint32_t)b) << 16;
  return v.f;
}

// ---------------- GroupNorm stats ----------------
__global__ void k_stats(const float* __restrict__ x, float* __restrict__ part) {
  __shared__ float ss[256], sq[256];
  const int t = threadIdx.x, b = blockIdx.x;
  const f32x4* p = (const f32x4*)(x + (size_t)b * 65536);
  float s = 0.f, qq = 0.f;
  for (int k = 0; k < 64; ++k) {
    f32x4 v = __builtin_nontemporal_load(p + t + 256 * k);
    s  += v[0] + v[1] + v[2] + v[3];
    qq += v[0] * v[0] + v[1] * v[1] + v[2] * v[2] + v[3] * v[3];
  }
  ss[t] = s; sq[t] = qq;
  __syncthreads();
  for (int st = 128; st > 0; st >>= 1) {
    if (t < st) { ss[t] += ss[t + st]; sq[t] += sq[t + st]; }
    __syncthreads();
  }
  if (t == 0) { part[2 * b] = ss[0]; part[2 * b + 1] = sq[0]; }
}

// ---------------- per-channel a,b ----------------
__global__ void k_coef(const float* __restrict__ part, const float* __restrict__ gn_w,
                       const float* __restrict__ gn_b, float* __restrict__ ab) {
  const int c = threadIdx.x;
  const int g = c >> 3;
  float s = 0.f, q = 0.f;
  for (int j = 0; j < 8; ++j) { s += part[(g * 8 + j) * 2]; q += part[(g * 8 + j) * 2 + 1]; }
  const float inv = 1.0f / 524288.0f;
  const float mean = s * inv;
  const float var = q * inv - mean * mean;
  const float rstd = rsqrtf(var + 1e-5f);
  const float a = gn_w[c] * rstd;
  ab[c] = a;
  ab[256 + c] = gn_b[c] - mean * a;
}

// ---------------- normalize + cast: writes BOTH layouts ----------------
__global__ void k_xn(const float* __restrict__ x, const float* __restrict__ ab,
                     unsigned short* __restrict__ xn, unsigned short* __restrict__ xnf) {
  __shared__ float tile[64][66];
  const int t = threadIdx.x;
  const int nb = blockIdx.x, cb = blockIdx.y;
  {
    const int cl = t >> 2, nc = t & 3;
    const int c = cb * 64 + cl;
    const float a = ab[c], b = ab[256 + c];
    const f32x4* src = (const f32x4*)(x + (size_t)c * NSP + nb * 64 + nc * 16);
#pragma unroll
    for (int j = 0; j < 4; ++j) {
      f32x4 v = __builtin_nontemporal_load(src + j);
      v = v * a + b;
      *(f32x4*)&tile[cl][nc * 16 + j * 4] = v;
    }
  }
  __syncthreads();
  // layout 1: row-major swizzled [n][c] for k_final
#pragma unroll
  for (int pass = 0; pass < 2; ++pass) {
    const int nl = pass * 32 + (t >> 3);
    const int ch = t & 7;
    const int u = ch ^ (nl & 7);
    union { unsigned short s[8]; u32x4 v; } pkv;
#pragma unroll
    for (int e = 0; e < 8; ++e) pkv.s[e] = f2bf(tile[u * 8 + e][nl]);
    *(u32x4*)(xn + (size_t)(nb * 64 + nl) * 256 + cb * 64 + ch * 8) = pkv.v;
  }
  // layout 2: fragment-native for k_kvctx
  {
    const int l = t & 63, w0 = t >> 6;
    u32x4* xnf4 = (u32x4*)xnf;
#pragma unroll
    for (int u2 = 0; u2 < 2; ++u2) {
      const int fp = w0 + u2 * 4;          // 0..7
      const int fl = fp >> 1, ksl = fp & 1;
      union { unsigned short s[8]; u32x4 v; } pk2;
#pragma unroll
      for (int e = 0; e < 8; ++e)
        pk2.s[e] = f2bf(tile[ksl * 32 + (l >> 4) * 8 + e][fl * 16 + (l & 15)]);
      xnf4[((size_t)(nb * 4 + fl) * 8 + cb * 2 + ksl) * 64 + l] = pk2.v;
    }
  }
}

// ---------------- pre-permute Wkv rows into MFMA B-fragment order ----------------
__global__ void k_wfrag(const float* __restrict__ qkv_w, unsigned short* __restrict__ wf) {
  const int blk = blockIdx.x;                 // blk = ks*64 + cf
  const int l = threadIdx.x;
  const int row = 512 + (blk & 63) * 16 + (l & 15);
  const int c0 = (blk >> 6) * 32 + (l >> 4) * 8;
  const float* src = qkv_w + (size_t)row * 256 + c0;
  union { unsigned short s[8]; u32x4 v; } u;
#pragma unroll
  for (int j = 0; j < 8; ++j) u.s[j] = f2bf(src[j]);
  *(u32x4*)(wf + ((size_t)blk * 64 + l) * 8) = u.v;
}

// ---------------- fused KV-GEMM + exp + in-register context, wfrag in LDS ----------------
__launch_bounds__(512, 2)
__global__ void k_kvctx(const unsigned short* __restrict__ xnf,
                        const unsigned short* __restrict__ wfrag,
                        const float* __restrict__ qkv_b,
                        float* __restrict__ sump, float* __restrict__ ctxp) {
  __shared__ __align__(16) char lds[133120];   // 128KB wfrag (later ctx dump) + 2KB srow
  const int t = threadIdx.x;
  const int w = t >> 6, l = t & 63;
  const int q = l & 15, lg = l >> 4;
  const int grp = blockIdx.x >> 6;             // 0..3  (2 heads each)
  const int chunk = blockIdx.x & 63;           // 0..63 (1024 rows each)
  const int hl = w >> 2, ws4 = w & 3;          // head-local, n-slice wave
  const int h = grp * 2 + hl;

  // load 2-head wfrag slice (128 KB) into LDS once
  {
    const u32x4* wsrc = (const u32x4*)wfrag;
    u32x4* wdst = (u32x4*)lds;
#pragma unroll
    for (int r = 0; r < 16; ++r) {
      const int ph = r >> 3, ks = r & 7;
      wdst[r * 512 + t] = wsrc[((size_t)ks * 64 + ph * 32 + grp * 8) * 64 + t];
    }
  }
  __syncthreads();

  const f32x4 fz = {0.f, 0.f, 0.f, 0.f};
  f32x4 ctxa[4][4];
#pragma unroll
  for (int a = 0; a < 4; ++a)
#pragma unroll
    for (int b = 0; b < 4; ++b) ctxa[a][b] = fz;
  float srow[4] = {0.f, 0.f, 0.f, 0.f};
  float bk[4], bv[4];
#pragma unroll
  for (int jj = 0; jj < 4; ++jj) {
    bk[jj] = qkv_b[512 + h * 64 + jj * 16 + q];
    bv[jj] = qkv_b[1024 + h * 64 + jj * 16 + q];
  }

  for (int it = 0; it < 4; ++it) {
    const int sl = chunk * 16 + ws4 * 4 + it;  // 64-row slice id
    f32x4 acc[4][4];
#pragma unroll
    for (int a = 0; a < 4; ++a)
#pragma unroll
      for (int b = 0; b < 4; ++b) acc[a][b] = fz;

    // K phase
#pragma unroll
    for (int ks = 0; ks < 8; ++ks) {
      bf16x8 xa[4];
#pragma unroll
      for (int i = 0; i < 4; ++i)
        xa[i] = *(const bf16x8*)(xnf + (((size_t)(sl * 4 + i) * 8 + ks) * 64 + l) * 8);
#pragma unroll
      for (int jj = 0; jj < 4; ++jj) {
        const bf16x8 bw = *(const bf16x8*)(lds + (((0 * 8 + ks) * 8 + hl * 4 + jj) * 64 + l) * 16);
#pragma unroll
        for (int i = 0; i < 4; ++i)
          acc[i][jj] = __builtin_amdgcn_mfma_f32_16x16x32_bf16(xa[i], bw, acc[i][jj], 0, 0, 0);
      }
    }
    bf16x8 pk[4][2];
#pragma unroll
    for (int jj = 0; jj < 4; ++jj) {
      float s = 0.f;
#pragma unroll
      for (int i0 = 0; i0 < 2; ++i0) {
        bf16x8 p;
#pragma unroll
        for (int r = 0; r < 4; ++r) {
          const unsigned short u0 = f2bf(__expf(acc[2 * i0][jj][r] + bk[jj]));
          const unsigned short u1 = f2bf(__expf(acc[2 * i0 + 1][jj][r] + bk[jj]));
          p[r] = (short)u0; p[r + 4] = (short)u1;
          s += bf2f(u0) + bf2f(u1);
        }
        pk[jj][i0] = p;
      }
      srow[jj] += s;
    }

    // V phase
#pragma unroll
    for (int a = 0; a < 4; ++a)
#pragma unroll
      for (int b = 0; b < 4; ++b) acc[a][b] = fz;
#pragma unroll
    for (int ks = 0; ks < 8; ++ks) {
      bf16x8 xa[4];
#pragma unroll
      for (int i = 0; i < 4; ++i)
        xa[i] = *(const bf16x8*)(xnf + (((size_t)(sl * 4 + i) * 8 + ks) * 64 + l) * 8);
#pragma unroll
      for (int jj = 0; jj < 4; ++jj) {
        const bf16x8 bw = *(const bf16x8*)(lds + (((1 * 8 + ks) * 8 + hl * 4 + jj) * 64 + l) * 16);
#pragma unroll
        for (int i = 0; i < 4; ++i)
          acc[i][jj] = __builtin_amdgcn_mfma_f32_16x16x32_bf16(xa[i], bw, acc[i][jj], 0, 0, 0);
      }
    }
    bf16x8 pv[4][2];
#pragma unroll
    for (int jj = 0; jj < 4; ++jj) {
#pragma unroll
      for (int i0 = 0; i0 < 2; ++i0) {
        bf16x8 p;
#pragma unroll
        for (int r = 0; r < 4; ++r) {
          p[r]     = (short)f2bf(acc[2 * i0][jj][r] + bv[jj]);
          p[r + 4] = (short)f2bf(acc[2 * i0 + 1][jj][r] + bv[jj]);
        }
        pv[jj][i0] = p;
      }
    }

    // context accumulate
#pragma unroll
    for (int i0 = 0; i0 < 2; ++i0)
#pragma unroll
      for (int ja = 0; ja < 4; ++ja)
#pragma unroll
        for (int jb = 0; jb < 4; ++jb)
          ctxa[ja][jb] = __builtin_amdgcn_mfma_f32_16x16x32_bf16(pk[ja][i0], pv[jb][i0], ctxa[ja][jb], 0, 0, 0);
  }

  // ---- block-level reduction ----
  __syncthreads();                 // all waves done reading wfrag LDS
  {
    float* dw = (float*)lds + w * 4096 + l * 4;
#pragma unroll
    for (int ja = 0; ja < 4; ++ja)
#pragma unroll
      for (int jb = 0; jb < 4; ++jb)
        *(f32x4*)(dw + (ja * 4 + jb) * 256) = ctxa[ja][jb];
  }
  {
    float* srl = (float*)(lds + 131072);
#pragma unroll
    for (int jj = 0; jj < 4; ++jj) {
      float s = srow[jj];
      s += __shfl_xor(s, 16, 64);
      s += __shfl_xor(s, 32, 64);
      if (l < 16) srl[w * 64 + jj * 16 + q] = s;
    }
  }
  __syncthreads();
  {
    const float* dump = (const float*)lds;
#pragma unroll
    for (int j = 0; j < 4; ++j) {
      const int m4 = j * 512 + t;            // 0..2048 f32x4 outputs
      const int hh = m4 >> 10, p4 = m4 & 1023;
      f32x4 s = *(const f32x4*)(dump + ((hh * 4 + 0) * 4096) + p4 * 4)
              + *(const f32x4*)(dump + ((hh * 4 + 1) * 4096) + p4 * 4)
              + *(const f32x4*)(dump + ((hh * 4 + 2) * 4096) + p4 * 4)
              + *(const f32x4*)(dump + ((hh * 4 + 3) * 4096) + p4 * 4);
      *(f32x4*)(ctxp + (((size_t)(grp * 2 + hh) * 64 + chunk) * 1024 + p4) * 4) = s;
    }
    if (t < 128) {
      const float* srl = (const float*)(lds + 131072);
      const int hh = t >> 6, d = t & 63;
      float s = srl[(hh * 4 + 0) * 64 + d] + srl[(hh * 4 + 1) * 64 + d]
              + srl[(hh * 4 + 2) * 64 + d] + srl[(hh * 4 + 3) * 64 + d];
      sump[((size_t)(grp * 2 + hh) * 64 + d) * 64 + chunk] = s;
    }
  }
}

// ---------------- reduce partials over 64 chunks ----------------
__global__ void k_ctxred(const float* __restrict__ ctxp, const float* __restrict__ sump,
                         float* __restrict__ ctx, float* __restrict__ sexp) {
  const int t = threadIdx.x;
  if (blockIdx.x < 64) {
    const int m4 = blockIdx.x * 128 + t;     // 0..8192
    const int h = m4 >> 10, p4 = m4 & 1023;
    f32x4 s = {0.f, 0.f, 0.f, 0.f};
#pragma unroll 8
    for (int c = 0; c < 64; ++c)
      s += *(const f32x4*)(ctxp + (((size_t)h * 64 + c) * 1024 + p4) * 4);
    const int jajb = p4 >> 6, ll = p4 & 63;
    const int ja = jajb >> 2, jb = jajb & 3;
    const int gg = ll >> 4, qq = ll & 15;
    float* cw = ctx + ((size_t)h * 64 + ja * 16 + gg * 4) * 64 + jb * 16 + qq;
    cw[0] = s[0]; cw[64] = s[1]; cw[128] = s[2]; cw[192] = s[3];
  } else {
    const int r = (blockIdx.x - 64) * 128 + t;
    float s = 0.f;
#pragma unroll 8
    for (int c = 0; c < 64; ++c) s += sump[(size_t)r * 64 + c];
    sexp[r] = s;
  }
}

// ---------------- W2 ----------------
__global__ void k_w2(const float* __restrict__ out_w, const float* __restrict__ ctx,
                     const float* __restrict__ sexp, float* __restrict__ w2) {
  const int r = blockIdx.x;
  const int h = r >> 6, d = r & 63;
  __shared__ float row[64];
  __shared__ float sinv;
  const int t = threadIdx.x;
  if (t < 64) row[t] = ctx[((size_t)h * 64 + d) * 64 + t];
  if (t == 0) sinv = 1.0f / sexp[r];
  __syncthreads();
  float a = 0.f;
  const float* wp = out_w + (size_t)t * 512 + h * 64;
#pragma unroll 8
  for (int e = 0; e < 64; ++e) a += wp[e] * row[e];
  w2[(size_t)t * 512 + r] = a * sinv;
}

// ---------------- Weff = W2 @ Wq ----------------
__global__ void k_weff(const float* __restrict__ w2, const float* __restrict__ qkv_w,
                       float* __restrict__ weff) {
  const int o = blockIdx.x;
  const int c = threadIdx.x;
  __shared__ float row[512];
  row[c] = w2[(size_t)o * 512 + c];
  row[256 + c] = w2[(size_t)o * 512 + 256 + c];
  __syncthreads();
  float a = 0.f;
#pragma unroll 8
  for (int r = 0; r < 512; ++r) a += row[r] * qkv_w[(size_t)r * 256 + c];
  weff[o * 256 + c] = a;
}

// ---------------- Weff -> fragment order ----------------
__global__ void k_wefrag(const float* __restrict__ weff, unsigned short* __restrict__ wf) {
  const int blk = blockIdx.x;
  const int l = threadIdx.x;
  const int row = (blk & 15) * 16 + (l & 15);
  const int c0 = (blk >> 4) * 32 + (l >> 4) * 8;
  const float* src = weff + (size_t)row * 256 + c0;
  union { unsigned short s[8]; u32x4 v; } u;
#pragma unroll
  for (int j = 0; j < 8; ++j) u.s[j] = f2bf(src[j]);
  *(u32x4*)(wf + ((size_t)blk * 64 + l) * 8) = u.v;
}

// ---------------- beff ----------------
__global__ void k_beff(const float* __restrict__ w2, const float* __restrict__ qkv_b,
                       const float* __restrict__ out_b, float* __restrict__ beff) {
  const int o = threadIdx.x;
  float a = out_b[o];
#pragma unroll 8
  for (int r = 0; r < 512; ++r) a += w2[(size_t)o * 512 + r] * qkv_b[r];
  beff[o] = a;
}

// ---------------- final GEMM + coalesced epilogue ----------------
__launch_bounds__(256, 2)
__global__ void k_final(const unsigned short* __restrict__ xn,
                        const unsigned short* __restrict__ wef,
                        const float* __restrict__ beff,
                        float* __restrict__ out) {
  __shared__ unsigned short xlds[32768];   // 64 KB staging, reused for transpose
  const int t = threadIdx.x;
  const int w = t >> 6, l = t & 63;
  const int q = l & 15, g = l >> 4;
  const int si = w >> 1, sj = w & 1;
  const size_t n0 = (size_t)blockIdx.x * 128;
  {
    const u32x4* gs = (const u32x4*)(xn + n0 * 256);
    u32x4* ld = (u32x4*)xlds;
#pragma unroll
    for (int k2 = 0; k2 < 16; ++k2) {
      u32x4 v = __builtin_nontemporal_load(gs + t + 256 * k2);
      ld[t + 256 * k2] = v;
    }
  }
  __syncthreads();
  const f32x4 fz = {0.f, 0.f, 0.f, 0.f};
  f32x4 acc[4][8];
#pragma unroll
  for (int i = 0; i < 4; ++i)
#pragma unroll
    for (int j = 0; j < 8; ++j) acc[i][j] = fz;
#pragma unroll
  for (int ks = 0; ks < 8; ++ks) {
    bf16x8 xa[4];
#pragma unroll
    for (int i = 0; i < 4; ++i) {
      const int nl = si * 64 + i * 16 + q;
      const int boff = nl * 512 + ((ks * 64 + g * 16) ^ ((nl & 7) << 4));
      xa[i] = *(const bf16x8*)((const char*)xlds + boff);
    }
#pragma unroll
    for (int jj = 0; jj < 8; ++jj) {
      const bf16x8 bw = *(const bf16x8*)(wef + (((size_t)(ks * 16 + sj * 8 + jj)) * 64 + l) * 8);
#pragma unroll
      for (int i = 0; i < 4; ++i)
        acc[i][jj] = __builtin_amdgcn_mfma_f32_16x16x32_bf16(xa[i], bw, acc[i][jj], 0, 0, 0);
    }
  }
  // transpose epilogue through LDS: 4 rounds of 64 output rows
  __syncthreads();
  float* trf = (float*)xlds;               // [64][129] floats
#pragma unroll
  for (int k4 = 0; k4 < 4; ++k4) {
    if ((k4 >> 1) == sj) {
#pragma unroll
      for (int jj2 = 0; jj2 < 4; ++jj2) {
        const int jj = (k4 & 1) * 4 + jj2;
        const float be = beff[sj * 128 + jj * 16 + q];
#pragma unroll
        for (int i = 0; i < 4; ++i)
#pragma unroll
          for (int r = 0; r < 4; ++r)
            trf[(jj2 * 16 + q) * 129 + si * 64 + i * 16 + g * 4 + r] = acc[i][jj][r] + be;
      }
    }
    __syncthreads();
#pragma unroll
    for (int j = 0; j < 32; ++j) {
      const int mm = j * 256 + t;          // 8192 floats
      const int ol = mm >> 7, cc = mm & 127;
      out[(size_t)(k4 * 64 + ol) * NSP + n0 + cc] = trf[ol * 129 + cc];
    }
    __syncthreads();
  }
}

extern "C" void kernel_launch(void* const* d_in, const int* in_sizes, int n_in,
                              void* d_out, int out_size, void* d_ws, size_t ws_size,
                              hipStream_t stream) {
  const float* x     = (const float*)d_in[0];
  const float* gn_w  = (const float*)d_in[1];
  const float* gn_b  = (const float*)d_in[2];
  const float* qkv_w = (const float*)d_in[3];
  const float* qkv_b = (const float*)d_in[4];
  const float* out_w = (const float*)d_in[5];
  const float* out_b = (const float*)d_in[6];
  char* ws = (char*)d_ws;
  unsigned short* xn  = (unsigned short*)(ws + WS_XN);
  unsigned short* wf  = (unsigned short*)(ws + WS_WFRAG);
  unsigned short* wef = (unsigned short*)(ws + WS_WEFRAG);
  float* part   = (float*)(ws + WS_PART);
  float* ab     = (float*)(ws + WS_AB);
  float* ctx    = (float*)(ws + WS_CTX);
  float* w2     = (float*)(ws + WS_W2);
  float* weff   = (float*)(ws + WS_WEFF);
  float* beff   = (float*)(ws + WS_BEFF);
  float* out    = (float*)d_out;
  // d_out scratch (fully overwritten by k_final):
  unsigned short* xnf = (unsigned short*)d_out;             // 32 MB
  float* ctxp = (float*)((char*)d_out + 33554432ULL);       //  8 MB
  float* sump = (float*)((char*)d_out + 41943040ULL);       // 128 KB

  k_wfrag<<<512, 64, 0, stream>>>(qkv_w, wf);
  k_stats<<<256, 256, 0, stream>>>(x, part);
  k_coef<<<1, 256, 0, stream>>>(part, gn_w, gn_b, ab);
  k_xn<<<dim3(1024, 4), 256, 0, stream>>>(x, ab, xn, xnf);
  k_kvctx<<<256, 512, 0, stream>>>(xnf, wf, qkv_b, sump, ctxp);
  k_ctxred<<<68, 128, 0, stream>>>(ctxp, sump, ctx, part);
  k_w2<<<512, 256, 0, stream>>>(out_w, ctx, part, w2);
  k_weff<<<256, 256, 0, stream>>>(w2, qkv_w, weff);
  k_wefrag<<<128, 64, 0, stream>>>(weff, wef);
  k_beff<<<1, 256, 0, stream>>>(w2, qkv_b, out_b, beff);
  k_final<<<512, 256, 0, stream>>>(xn, wef, beff, out);
}

// Round 7
// 396.676 us; speedup vs baseline: 1.2670x; 1.0333x over previous
//
#include <hip/hip_runtime.h>
#include <stdint.h>

typedef __attribute__((ext_vector_type(8))) short bf16x8;
typedef __attribute__((ext_vector_type(4))) float f32x4;
typedef __attribute__((ext_vector_type(4))) unsigned int u32x4;

#define NSP 65536

// workspace byte offsets
#define WS_XN     0ULL         // 33554432  bf16 xnT swizzled [n][c]   (k_final)
#define WS_WFRAG  33554432ULL  // 524288    Wkv fragment buffer
#define WS_WEFRAG 34078720ULL  // 131072    Weff fragment buffer
#define WS_PART   34209792ULL  // 2048      stats partials -> reduced sumexp[512]
#define WS_AB     34211840ULL  // 2048      per-channel a,b
#define WS_CTX    34215936ULL  // 131072    ctx[8][64][64]
#define WS_W2     34347008ULL  // 1048576   W2[256][512]
#define WS_WEFF   35395584ULL  // 262144    Weff[256][256]
#define WS_BEFF   35657728ULL  // 1024      beff[256]

// d_out doubles as scratch before k_final overwrites it:
//   xnf  (bf16) [0 .. 32MB)       fragment-native xn for k_kvctx
//   ctxp (f32)  [32MB .. 40MB)    8 heads * 64 chunks * 4096 partials
//   sump (f32)  [40MB .. +128KB)  [h*64+d][chunk]

__device__ __forceinline__ unsigned short f2bf(float f) {
  union { float f; uint32_t u; } v; v.f = f;
  uint32_t r = v.u + 0x7FFFu + ((v.u >> 16) & 1u);
  return (unsigned short)(r >> 16);
}
__device__ __forceinline__ float bf2f(unsigned short b) {
  union { uint32_t u; float f; } v; v.u = ((uint32_t)b) << 16;
  return v.f;
}

// ---------------- GroupNorm stats ----------------
__global__ void k_stats(const float* __restrict__ x, float* __restrict__ part) {
  __shared__ float ss[256], sq[256];
  const int t = threadIdx.x, b = blockIdx.x;
  const f32x4* p = (const f32x4*)(x + (size_t)b * 65536);
  float s = 0.f, qq = 0.f;
  for (int k = 0; k < 64; ++k) {
    f32x4 v = __builtin_nontemporal_load(p + t + 256 * k);
    s  += v[0] + v[1] + v[2] + v[3];
    qq += v[0] * v[0] + v[1] * v[1] + v[2] * v[2] + v[3] * v[3];
  }
  ss[t] = s; sq[t] = qq;
  __syncthreads();
  for (int st = 128; st > 0; st >>= 1) {
    if (t < st) { ss[t] += ss[t + st]; sq[t] += sq[t + st]; }
    __syncthreads();
  }
  if (t == 0) { part[2 * b] = ss[0]; part[2 * b + 1] = sq[0]; }
}

// ---------------- per-channel a,b ----------------
__global__ void k_coef(const float* __restrict__ part, const float* __restrict__ gn_w,
                       const float* __restrict__ gn_b, float* __restrict__ ab) {
  const int c = threadIdx.x;
  const int g = c >> 3;
  float s = 0.f, q = 0.f;
  for (int j = 0; j < 8; ++j) { s += part[(g * 8 + j) * 2]; q += part[(g * 8 + j) * 2 + 1]; }
  const float inv = 1.0f / 524288.0f;
  const float mean = s * inv;
  const float var = q * inv - mean * mean;
  const float rstd = rsqrtf(var + 1e-5f);
  const float a = gn_w[c] * rstd;
  ab[c] = a;
  ab[256 + c] = gn_b[c] - mean * a;
}

// ---------------- normalize + cast: writes BOTH layouts ----------------
__global__ void k_xn(const float* __restrict__ x, const float* __restrict__ ab,
                     unsigned short* __restrict__ xn, unsigned short* __restrict__ xnf) {
  __shared__ float tile[64][66];
  const int t = threadIdx.x;
  const int nb = blockIdx.x, cb = blockIdx.y;
  {
    const int cl = t >> 2, nc = t & 3;
    const int c = cb * 64 + cl;
    const float a = ab[c], b = ab[256 + c];
    const f32x4* src = (const f32x4*)(x + (size_t)c * NSP + nb * 64 + nc * 16);
#pragma unroll
    for (int j = 0; j < 4; ++j) {
      f32x4 v = __builtin_nontemporal_load(src + j);
      v = v * a + b;
      *(f32x4*)&tile[cl][nc * 16 + j * 4] = v;
    }
  }
  __syncthreads();
  // layout 1: row-major swizzled [n][c] for k_final
#pragma unroll
  for (int pass = 0; pass < 2; ++pass) {
    const int nl = pass * 32 + (t >> 3);
    const int ch = t & 7;
    const int u = ch ^ (nl & 7);
    union { unsigned short s[8]; u32x4 v; } pkv;
#pragma unroll
    for (int e = 0; e < 8; ++e) pkv.s[e] = f2bf(tile[u * 8 + e][nl]);
    *(u32x4*)(xn + (size_t)(nb * 64 + nl) * 256 + cb * 64 + ch * 8) = pkv.v;
  }
  // layout 2: fragment-native for k_kvctx
  {
    const int l = t & 63, w0 = t >> 6;
    u32x4* xnf4 = (u32x4*)xnf;
#pragma unroll
    for (int u2 = 0; u2 < 2; ++u2) {
      const int fp = w0 + u2 * 4;          // 0..7
      const int fl = fp >> 1, ksl = fp & 1;
      union { unsigned short s[8]; u32x4 v; } pk2;
#pragma unroll
      for (int e = 0; e < 8; ++e)
        pk2.s[e] = f2bf(tile[ksl * 32 + (l >> 4) * 8 + e][fl * 16 + (l & 15)]);
      xnf4[((size_t)(nb * 4 + fl) * 8 + cb * 2 + ksl) * 64 + l] = pk2.v;
    }
  }
}

// ---------------- pre-permute Wkv rows into MFMA B-fragment order ----------------
__global__ void k_wfrag(const float* __restrict__ qkv_w, unsigned short* __restrict__ wf) {
  const int blk = blockIdx.x;                 // blk = ks*64 + cf
  const int l = threadIdx.x;
  const int row = 512 + (blk & 63) * 16 + (l & 15);
  const int c0 = (blk >> 6) * 32 + (l >> 4) * 8;
  const float* src = qkv_w + (size_t)row * 256 + c0;
  union { unsigned short s[8]; u32x4 v; } u;
#pragma unroll
  for (int j = 0; j < 8; ++j) u.s[j] = f2bf(src[j]);
  *(u32x4*)(wf + ((size_t)blk * 64 + l) * 8) = u.v;
}

// ---------------- fused KV-GEMM + exp + in-register context, wfrag in LDS ----------------
// launch_bounds (512,1): 256-VGPR budget -> no scratch spill (live set ~220)
__launch_bounds__(512, 1)
__global__ void k_kvctx(const unsigned short* __restrict__ xnf,
                        const unsigned short* __restrict__ wfrag,
                        const float* __restrict__ qkv_b,
                        float* __restrict__ sump, float* __restrict__ ctxp) {
  __shared__ __align__(16) char lds[133120];   // 128KB wfrag (later ctx dump) + 2KB srow
  const int t = threadIdx.x;
  const int w = t >> 6, l = t & 63;
  const int q = l & 15;
  const int grp = blockIdx.x >> 6;             // 0..3  (2 heads each)
  const int chunk = blockIdx.x & 63;           // 0..63 (1024 rows each)
  const int hl = w >> 2, ws4 = w & 3;          // head-local, n-slice wave
  const int h = grp * 2 + hl;

  // load 2-head wfrag slice (128 KB) into LDS once
  {
    const u32x4* wsrc = (const u32x4*)wfrag;
    u32x4* wdst = (u32x4*)lds;
#pragma unroll
    for (int r = 0; r < 16; ++r) {
      const int ph = r >> 3, ks = r & 7;
      wdst[r * 512 + t] = wsrc[((size_t)ks * 64 + ph * 32 + grp * 8) * 64 + t];
    }
  }
  __syncthreads();

  const f32x4 fz = {0.f, 0.f, 0.f, 0.f};
  f32x4 ctxa[4][4];
#pragma unroll
  for (int a = 0; a < 4; ++a)
#pragma unroll
    for (int b = 0; b < 4; ++b) ctxa[a][b] = fz;
  float srow[4] = {0.f, 0.f, 0.f, 0.f};
  float bk[4], bv[4];
#pragma unroll
  for (int jj = 0; jj < 4; ++jj) {
    bk[jj] = qkv_b[512 + h * 64 + jj * 16 + q];
    bv[jj] = qkv_b[1024 + h * 64 + jj * 16 + q];
  }

  for (int it = 0; it < 4; ++it) {
    const int sl = chunk * 16 + ws4 * 4 + it;  // 64-row slice id
    f32x4 acc[4][4];
#pragma unroll
    for (int a = 0; a < 4; ++a)
#pragma unroll
      for (int b = 0; b < 4; ++b) acc[a][b] = fz;

    // K phase
#pragma unroll
    for (int ks = 0; ks < 8; ++ks) {
      bf16x8 xa[4];
#pragma unroll
      for (int i = 0; i < 4; ++i)
        xa[i] = *(const bf16x8*)(xnf + (((size_t)(sl * 4 + i) * 8 + ks) * 64 + l) * 8);
#pragma unroll
      for (int jj = 0; jj < 4; ++jj) {
        const bf16x8 bw = *(const bf16x8*)(lds + (((0 * 8 + ks) * 8 + hl * 4 + jj) * 64 + l) * 16);
#pragma unroll
        for (int i = 0; i < 4; ++i)
          acc[i][jj] = __builtin_amdgcn_mfma_f32_16x16x32_bf16(xa[i], bw, acc[i][jj], 0, 0, 0);
      }
    }
    bf16x8 pk[4][2];
#pragma unroll
    for (int jj = 0; jj < 4; ++jj) {
      float s = 0.f;
#pragma unroll
      for (int i0 = 0; i0 < 2; ++i0) {
        bf16x8 p;
#pragma unroll
        for (int r = 0; r < 4; ++r) {
          const unsigned short u0 = f2bf(__expf(acc[2 * i0][jj][r] + bk[jj]));
          const unsigned short u1 = f2bf(__expf(acc[2 * i0 + 1][jj][r] + bk[jj]));
          p[r] = (short)u0; p[r + 4] = (short)u1;
          s += bf2f(u0) + bf2f(u1);
        }
        pk[jj][i0] = p;
      }
      srow[jj] += s;
    }

    // V phase
#pragma unroll
    for (int a = 0; a < 4; ++a)
#pragma unroll
      for (int b = 0; b < 4; ++b) acc[a][b] = fz;
#pragma unroll
    for (int ks = 0; ks < 8; ++ks) {
      bf16x8 xa[4];
#pragma unroll
      for (int i = 0; i < 4; ++i)
        xa[i] = *(const bf16x8*)(xnf + (((size_t)(sl * 4 + i) * 8 + ks) * 64 + l) * 8);
#pragma unroll
      for (int jj = 0; jj < 4; ++jj) {
        const bf16x8 bw = *(const bf16x8*)(lds + (((1 * 8 + ks) * 8 + hl * 4 + jj) * 64 + l) * 16);
#pragma unroll
        for (int i = 0; i < 4; ++i)
          acc[i][jj] = __builtin_amdgcn_mfma_f32_16x16x32_bf16(xa[i], bw, acc[i][jj], 0, 0, 0);
      }
    }
    bf16x8 pv[4][2];
#pragma unroll
    for (int jj = 0; jj < 4; ++jj) {
#pragma unroll
      for (int i0 = 0; i0 < 2; ++i0) {
        bf16x8 p;
#pragma unroll
        for (int r = 0; r < 4; ++r) {
          p[r]     = (short)f2bf(acc[2 * i0][jj][r] + bv[jj]);
          p[r + 4] = (short)f2bf(acc[2 * i0 + 1][jj][r] + bv[jj]);
        }
        pv[jj][i0] = p;
      }
    }

    // context accumulate
#pragma unroll
    for (int i0 = 0; i0 < 2; ++i0)
#pragma unroll
      for (int ja = 0; ja < 4; ++ja)
#pragma unroll
        for (int jb = 0; jb < 4; ++jb)
          ctxa[ja][jb] = __builtin_amdgcn_mfma_f32_16x16x32_bf16(pk[ja][i0], pv[jb][i0], ctxa[ja][jb], 0, 0, 0);
  }

  // ---- block-level reduction ----
  __syncthreads();                 // all waves done reading wfrag LDS
  {
    float* dw = (float*)lds + w * 4096 + l * 4;
#pragma unroll
    for (int ja = 0; ja < 4; ++ja)
#pragma unroll
      for (int jb = 0; jb < 4; ++jb)
        *(f32x4*)(dw + (ja * 4 + jb) * 256) = ctxa[ja][jb];
  }
  {
    float* srl = (float*)(lds + 131072);
#pragma unroll
    for (int jj = 0; jj < 4; ++jj) {
      float s = srow[jj];
      s += __shfl_xor(s, 16, 64);
      s += __shfl_xor(s, 32, 64);
      if (l < 16) srl[w * 64 + jj * 16 + q] = s;
    }
  }
  __syncthreads();
  {
    const float* dump = (const float*)lds;
#pragma unroll
    for (int j = 0; j < 4; ++j) {
      const int m4 = j * 512 + t;            // 0..2048 f32x4 outputs
      const int hh = m4 >> 10, p4 = m4 & 1023;
      f32x4 s = *(const f32x4*)(dump + ((hh * 4 + 0) * 4096) + p4 * 4)
              + *(const f32x4*)(dump + ((hh * 4 + 1) * 4096) + p4 * 4)
              + *(const f32x4*)(dump + ((hh * 4 + 2) * 4096) + p4 * 4)
              + *(const f32x4*)(dump + ((hh * 4 + 3) * 4096) + p4 * 4);
      *(f32x4*)(ctxp + (((size_t)(grp * 2 + hh) * 64 + chunk) * 1024 + p4) * 4) = s;
    }
    if (t < 128) {
      const float* srl = (const float*)(lds + 131072);
      const int hh = t >> 6, d = t & 63;
      float s = srl[(hh * 4 + 0) * 64 + d] + srl[(hh * 4 + 1) * 64 + d]
              + srl[(hh * 4 + 2) * 64 + d] + srl[(hh * 4 + 3) * 64 + d];
      sump[((size_t)(grp * 2 + hh) * 64 + d) * 64 + chunk] = s;
    }
  }
}

// ---------------- reduce partials over 64 chunks ----------------
__global__ void k_ctxred(const float* __restrict__ ctxp, const float* __restrict__ sump,
                         float* __restrict__ ctx, float* __restrict__ sexp) {
  const int t = threadIdx.x;
  if (blockIdx.x < 64) {
    const int m4 = blockIdx.x * 128 + t;     // 0..8192
    const int h = m4 >> 10, p4 = m4 & 1023;
    f32x4 s = {0.f, 0.f, 0.f, 0.f};
#pragma unroll 8
    for (int c = 0; c < 64; ++c)
      s += *(const f32x4*)(ctxp + (((size_t)h * 64 + c) * 1024 + p4) * 4);
    const int jajb = p4 >> 6, ll = p4 & 63;
    const int ja = jajb >> 2, jb = jajb & 3;
    const int gg = ll >> 4, qq = ll & 15;
    float* cw = ctx + ((size_t)h * 64 + ja * 16 + gg * 4) * 64 + jb * 16 + qq;
    cw[0] = s[0]; cw[64] = s[1]; cw[128] = s[2]; cw[192] = s[3];
  } else {
    const int r = (blockIdx.x - 64) * 128 + t;
    float s = 0.f;
#pragma unroll 8
    for (int c = 0; c < 64; ++c) s += sump[(size_t)r * 64 + c];
    sexp[r] = s;
  }
}

// ---------------- W2 ----------------
__global__ void k_w2(const float* __restrict__ out_w, const float* __restrict__ ctx,
                     const float* __restrict__ sexp, float* __restrict__ w2) {
  const int r = blockIdx.x;
  const int h = r >> 6, d = r & 63;
  __shared__ float row[64];
  __shared__ float sinv;
  const int t = threadIdx.x;
  if (t < 64) row[t] = ctx[((size_t)h * 64 + d) * 64 + t];
  if (t == 0) sinv = 1.0f / sexp[r];
  __syncthreads();
  float a = 0.f;
  const float* wp = out_w + (size_t)t * 512 + h * 64;
#pragma unroll 8
  for (int e = 0; e < 64; ++e) a += wp[e] * row[e];
  w2[(size_t)t * 512 + r] = a * sinv;
}

// ---------------- Weff = W2 @ Wq ----------------
__global__ void k_weff(const float* __restrict__ w2, const float* __restrict__ qkv_w,
                       float* __restrict__ weff) {
  const int o = blockIdx.x;
  const int c = threadIdx.x;
  __shared__ float row[512];
  row[c] = w2[(size_t)o * 512 + c];
  row[256 + c] = w2[(size_t)o * 512 + 256 + c];
  __syncthreads();
  float a = 0.f;
#pragma unroll 8
  for (int r = 0; r < 512; ++r) a += row[r] * qkv_w[(size_t)r * 256 + c];
  weff[o * 256 + c] = a;
}

// ---------------- Weff -> fragment order ----------------
__global__ void k_wefrag(const float* __restrict__ weff, unsigned short* __restrict__ wf) {
  const int blk = blockIdx.x;
  const int l = threadIdx.x;
  const int row = (blk & 15) * 16 + (l & 15);
  const int c0 = (blk >> 4) * 32 + (l >> 4) * 8;
  const float* src = weff + (size_t)row * 256 + c0;
  union { unsigned short s[8]; u32x4 v; } u;
#pragma unroll
  for (int j = 0; j < 8; ++j) u.s[j] = f2bf(src[j]);
  *(u32x4*)(wf + ((size_t)blk * 64 + l) * 8) = u.v;
}

// ---------------- beff ----------------
__global__ void k_beff(const float* __restrict__ w2, const float* __restrict__ qkv_b,
                       const float* __restrict__ out_b, float* __restrict__ beff) {
  const int o = threadIdx.x;
  float a = out_b[o];
#pragma unroll 8
  for (int r = 0; r < 512; ++r) a += w2[(size_t)o * 512 + r] * qkv_b[r];
  beff[o] = a;
}

// ---------------- final GEMM + coalesced epilogue ----------------
__launch_bounds__(256, 2)
__global__ void k_final(const unsigned short* __restrict__ xn,
                        const unsigned short* __restrict__ wef,
                        const float* __restrict__ beff,
                        float* __restrict__ out) {
  __shared__ unsigned short xlds[32768];   // 64 KB staging, reused for transpose
  const int t = threadIdx.x;
  const int w = t >> 6, l = t & 63;
  const int q = l & 15, g = l >> 4;
  const int si = w >> 1, sj = w & 1;
  const size_t n0 = (size_t)blockIdx.x * 128;
  {
    const u32x4* gs = (const u32x4*)(xn + n0 * 256);
    u32x4* ld = (u32x4*)xlds;
#pragma unroll
    for (int k2 = 0; k2 < 16; ++k2) {
      u32x4 v = __builtin_nontemporal_load(gs + t + 256 * k2);
      ld[t + 256 * k2] = v;
    }
  }
  __syncthreads();
  const f32x4 fz = {0.f, 0.f, 0.f, 0.f};
  f32x4 acc[4][8];
#pragma unroll
  for (int i = 0; i < 4; ++i)
#pragma unroll
    for (int j = 0; j < 8; ++j) acc[i][j] = fz;
#pragma unroll
  for (int ks = 0; ks < 8; ++ks) {
    bf16x8 xa[4];
#pragma unroll
    for (int i = 0; i < 4; ++i) {
      const int nl = si * 64 + i * 16 + q;
      const int boff = nl * 512 + ((ks * 64 + g * 16) ^ ((nl & 7) << 4));
      xa[i] = *(const bf16x8*)((const char*)xlds + boff);
    }
#pragma unroll
    for (int jj = 0; jj < 8; ++jj) {
      const bf16x8 bw = *(const bf16x8*)(wef + (((size_t)(ks * 16 + sj * 8 + jj)) * 64 + l) * 8);
#pragma unroll
      for (int i = 0; i < 4; ++i)
        acc[i][jj] = __builtin_amdgcn_mfma_f32_16x16x32_bf16(xa[i], bw, acc[i][jj], 0, 0, 0);
    }
  }
  // transpose epilogue through LDS: 4 rounds of 64 output rows
  __syncthreads();
  float* trf = (float*)xlds;               // [64][129] floats
#pragma unroll
  for (int k4 = 0; k4 < 4; ++k4) {
    if ((k4 >> 1) == sj) {
#pragma unroll
      for (int jj2 = 0; jj2 < 4; ++jj2) {
        const int jj = (k4 & 1) * 4 + jj2;
        const float be = beff[sj * 128 + jj * 16 + q];
#pragma unroll
        for (int i = 0; i < 4; ++i)
#pragma unroll
          for (int r = 0; r < 4; ++r)
            trf[(jj2 * 16 + q) * 129 + si * 64 + i * 16 + g * 4 + r] = acc[i][jj][r] + be;
      }
    }
    __syncthreads();
#pragma unroll
    for (int j = 0; j < 32; ++j) {
      const int mm = j * 256 + t;          // 8192 floats
      const int ol = mm >> 7, cc = mm & 127;
      out[(size_t)(k4 * 64 + ol) * NSP + n0 + cc] = trf[ol * 129 + cc];
    }
    __syncthreads();
  }
}

extern "C" void kernel_launch(void* const* d_in, const int* in_sizes, int n_in,
                              void* d_out, int out_size, void* d_ws, size_t ws_size,
                              hipStream_t stream) {
  const float* x     = (const float*)d_in[0];
  const float* gn_w  = (const float*)d_in[1];
  const float* gn_b  = (const float*)d_in[2];
  const float* qkv_w = (const float*)d_in[3];
  const float* qkv_b = (const float*)d_in[4];
  const float* out_w = (const float*)d_in[5];
  const float* out_b = (const float*)d_in[6];
  char* ws = (char*)d_ws;
  unsigned short* xn  = (unsigned short*)(ws + WS_XN);
  unsigned short* wf  = (unsigned short*)(ws + WS_WFRAG);
  unsigned short* wef = (unsigned short*)(ws + WS_WEFRAG);
  float* part   = (float*)(ws + WS_PART);
  float* ab     = (float*)(ws + WS_AB);
  float* ctx    = (float*)(ws + WS_CTX);
  float* w2     = (float*)(ws + WS_W2);
  float* weff   = (float*)(ws + WS_WEFF);
  float* beff   = (float*)(ws + WS_BEFF);
  float* out    = (float*)d_out;
  // d_out scratch (fully overwritten by k_final):
  unsigned short* xnf = (unsigned short*)d_out;             // 32 MB
  float* ctxp = (float*)((char*)d_out + 33554432ULL);       //  8 MB
  float* sump = (float*)((char*)d_out + 41943040ULL);       // 128 KB

  k_wfrag<<<512, 64, 0, stream>>>(qkv_w, wf);
  k_stats<<<256, 256, 0, stream>>>(x, part);
  k_coef<<<1, 256, 0, stream>>>(part, gn_w, gn_b, ab);
  k_xn<<<dim3(1024, 4), 256, 0, stream>>>(x, ab, xn, xnf);
  k_kvctx<<<256, 512, 0, stream>>>(xnf, wf, qkv_b, sump, ctxp);
  k_ctxred<<<68, 128, 0, stream>>>(ctxp, sump, ctx, part);
  k_w2<<<512, 256, 0, stream>>>(out_w, ctx, part, w2);
  k_weff<<<256, 256, 0, stream>>>(w2, qkv_w, weff);
  k_wefrag<<<128, 64, 0, stream>>>(weff, wef);
  k_beff<<<1, 256, 0, stream>>>(w2, qkv_b, out_b, beff);
  k_final<<<512, 256, 0, stream>>>(xn, wef, beff, out);
}

// Round 8
// 297.274 us; speedup vs baseline: 1.6907x; 1.3344x over previous
//
#include <hip/hip_runtime.h>
#include <stdint.h>

typedef __attribute__((ext_vector_type(8))) short bf16x8;
typedef __attribute__((ext_vector_type(4))) float f32x4;
typedef __attribute__((ext_vector_type(4))) unsigned int u32x4;

#define NSP 65536

// workspace byte offsets
#define WS_XN     0ULL         // 33554432  bf16 xnT swizzled [n][c]   (k_final)
#define WS_WFRAG  33554432ULL  // 524288    Wkv fragment buffer
#define WS_WEFRAG 34078720ULL  // 131072    Weff fragment buffer
#define WS_PART   34209792ULL  // 2048      stats partials -> reduced sumexp[512]
#define WS_AB     34211840ULL  // 2048      per-channel a,b
#define WS_CTX    34215936ULL  // 131072    ctx[8][64][64]
#define WS_W2     34347008ULL  // 1048576   W2[256][512]
#define WS_WEFF   35395584ULL  // 262144    Weff[256][256]
#define WS_BEFF   35657728ULL  // 1024      beff[256]

// d_out doubles as scratch before k_final overwrites it:
//   xnf  (bf16) [0 .. 32MB)       fragment-native xn for k_kvctx
//   ctxp (f32)  [32MB .. 40MB)    8 heads * 64 chunks * 4096 partials
//   sump (f32)  [40MB .. +128KB)  [h*64+d][chunk]

__device__ __forceinline__ unsigned short f2bf(float f) {
  union { float f; uint32_t u; } v; v.f = f;
  uint32_t r = v.u + 0x7FFFu + ((v.u >> 16) & 1u);
  return (unsigned short)(r >> 16);
}
__device__ __forceinline__ float bf2f(unsigned short b) {
  union { uint32_t u; float f; } v; v.u = ((uint32_t)b) << 16;
  return v.f;
}

// ---------------- GroupNorm stats ----------------
__global__ void k_stats(const float* __restrict__ x, float* __restrict__ part) {
  __shared__ float ss[256], sq[256];
  const int t = threadIdx.x, b = blockIdx.x;
  const f32x4* p = (const f32x4*)(x + (size_t)b * 65536);
  float s = 0.f, qq = 0.f;
  for (int k = 0; k < 64; ++k) {
    f32x4 v = __builtin_nontemporal_load(p + t + 256 * k);
    s  += v[0] + v[1] + v[2] + v[3];
    qq += v[0] * v[0] + v[1] * v[1] + v[2] * v[2] + v[3] * v[3];
  }
  ss[t] = s; sq[t] = qq;
  __syncthreads();
  for (int st = 128; st > 0; st >>= 1) {
    if (t < st) { ss[t] += ss[t + st]; sq[t] += sq[t + st]; }
    __syncthreads();
  }
  if (t == 0) { part[2 * b] = ss[0]; part[2 * b + 1] = sq[0]; }
}

// ---------------- per-channel a,b ----------------
__global__ void k_coef(const float* __restrict__ part, const float* __restrict__ gn_w,
                       const float* __restrict__ gn_b, float* __restrict__ ab) {
  const int c = threadIdx.x;
  const int g = c >> 3;
  float s = 0.f, q = 0.f;
  for (int j = 0; j < 8; ++j) { s += part[(g * 8 + j) * 2]; q += part[(g * 8 + j) * 2 + 1]; }
  const float inv = 1.0f / 524288.0f;
  const float mean = s * inv;
  const float var = q * inv - mean * mean;
  const float rstd = rsqrtf(var + 1e-5f);
  const float a = gn_w[c] * rstd;
  ab[c] = a;
  ab[256 + c] = gn_b[c] - mean * a;
}

// ---------------- normalize + cast: writes BOTH layouts ----------------
__global__ void k_xn(const float* __restrict__ x, const float* __restrict__ ab,
                     unsigned short* __restrict__ xn, unsigned short* __restrict__ xnf) {
  __shared__ float tile[64][66];
  const int t = threadIdx.x;
  const int nb = blockIdx.x, cb = blockIdx.y;
  {
    const int cl = t >> 2, nc = t & 3;
    const int c = cb * 64 + cl;
    const float a = ab[c], b = ab[256 + c];
    const f32x4* src = (const f32x4*)(x + (size_t)c * NSP + nb * 64 + nc * 16);
#pragma unroll
    for (int j = 0; j < 4; ++j) {
      f32x4 v = __builtin_nontemporal_load(src + j);
      v = v * a + b;
      *(f32x4*)&tile[cl][nc * 16 + j * 4] = v;
    }
  }
  __syncthreads();
  // layout 1: row-major swizzled [n][c] for k_final
#pragma unroll
  for (int pass = 0; pass < 2; ++pass) {
    const int nl = pass * 32 + (t >> 3);
    const int ch = t & 7;
    const int u = ch ^ (nl & 7);
    union { unsigned short s[8]; u32x4 v; } pkv;
#pragma unroll
    for (int e = 0; e < 8; ++e) pkv.s[e] = f2bf(tile[u * 8 + e][nl]);
    *(u32x4*)(xn + (size_t)(nb * 64 + nl) * 256 + cb * 64 + ch * 8) = pkv.v;
  }
  // layout 2: fragment-native for k_kvctx
  {
    const int l = t & 63, w0 = t >> 6;
    u32x4* xnf4 = (u32x4*)xnf;
#pragma unroll
    for (int u2 = 0; u2 < 2; ++u2) {
      const int fp = w0 + u2 * 4;          // 0..7
      const int fl = fp >> 1, ksl = fp & 1;
      union { unsigned short s[8]; u32x4 v; } pk2;
#pragma unroll
      for (int e = 0; e < 8; ++e)
        pk2.s[e] = f2bf(tile[ksl * 32 + (l >> 4) * 8 + e][fl * 16 + (l & 15)]);
      xnf4[((size_t)(nb * 4 + fl) * 8 + cb * 2 + ksl) * 64 + l] = pk2.v;
    }
  }
}

// ---------------- pre-permute Wkv rows into MFMA B-fragment order ----------------
__global__ void k_wfrag(const float* __restrict__ qkv_w, unsigned short* __restrict__ wf) {
  const int blk = blockIdx.x;                 // blk = ks*64 + cf
  const int l = threadIdx.x;
  const int row = 512 + (blk & 63) * 16 + (l & 15);
  const int c0 = (blk >> 6) * 32 + (l >> 4) * 8;
  const float* src = qkv_w + (size_t)row * 256 + c0;
  union { unsigned short s[8]; u32x4 v; } u;
#pragma unroll
  for (int j = 0; j < 8; ++j) u.s[j] = f2bf(src[j]);
  *(u32x4*)(wf + ((size_t)blk * 64 + l) * 8) = u.v;
}

// ---------------- fused KV-GEMM + exp + in-register context, wfrag in LDS ----------------
// 32-row steps: acc[2][4]+pk[4]+pv[4]+xa[2] keeps live set ~140 regs -> no spill
__launch_bounds__(512, 1)
__global__ void k_kvctx(const unsigned short* __restrict__ xnf,
                        const unsigned short* __restrict__ wfrag,
                        const float* __restrict__ qkv_b,
                        float* __restrict__ sump, float* __restrict__ ctxp) {
  __shared__ __align__(16) char lds[133120];   // 128KB wfrag (later ctx dump) + 2KB srow
  const int t = threadIdx.x;
  const int w = t >> 6, l = t & 63;
  const int q = l & 15;
  const int grp = blockIdx.x >> 6;             // 0..3  (2 heads each)
  const int chunk = blockIdx.x & 63;           // 0..63 (1024 rows each)
  const int hl = w >> 2, ws4 = w & 3;          // head-local, n-slice wave
  const int h = grp * 2 + hl;

  // load 2-head wfrag slice (128 KB) into LDS once
  {
    const u32x4* wsrc = (const u32x4*)wfrag;
    u32x4* wdst = (u32x4*)lds;
#pragma unroll
    for (int r = 0; r < 16; ++r) {
      const int ph = r >> 3, ks = r & 7;
      wdst[r * 512 + t] = wsrc[((size_t)ks * 64 + ph * 32 + grp * 8) * 64 + t];
    }
  }
  __syncthreads();

  const f32x4 fz = {0.f, 0.f, 0.f, 0.f};
  f32x4 ctxa[4][4];
#pragma unroll
  for (int a = 0; a < 4; ++a)
#pragma unroll
    for (int b = 0; b < 4; ++b) ctxa[a][b] = fz;
  float srow[4] = {0.f, 0.f, 0.f, 0.f};
  float bk[4], bv[4];
#pragma unroll
  for (int jj = 0; jj < 4; ++jj) {
    bk[jj] = qkv_b[512 + h * 64 + jj * 16 + q];
    bv[jj] = qkv_b[1024 + h * 64 + jj * 16 + q];
  }

  for (int it = 0; it < 8; ++it) {
    const int nr0 = chunk * 64 + ws4 * 16 + it * 2;   // 16-row group id (2 groups/step)
    f32x4 acc[2][4];
#pragma unroll
    for (int a = 0; a < 2; ++a)
#pragma unroll
      for (int b = 0; b < 4; ++b) acc[a][b] = fz;

    // K phase
#pragma unroll
    for (int ks = 0; ks < 8; ++ks) {
      const bf16x8 xa0 = *(const bf16x8*)(xnf + (((size_t)(nr0 + 0) * 8 + ks) * 64 + l) * 8);
      const bf16x8 xa1 = *(const bf16x8*)(xnf + (((size_t)(nr0 + 1) * 8 + ks) * 64 + l) * 8);
#pragma unroll
      for (int jj = 0; jj < 4; ++jj) {
        const bf16x8 bw = *(const bf16x8*)(lds + (((0 * 8 + ks) * 8 + hl * 4 + jj) * 64 + l) * 16);
        acc[0][jj] = __builtin_amdgcn_mfma_f32_16x16x32_bf16(xa0, bw, acc[0][jj], 0, 0, 0);
        acc[1][jj] = __builtin_amdgcn_mfma_f32_16x16x32_bf16(xa1, bw, acc[1][jj], 0, 0, 0);
      }
    }
    bf16x8 pk[4];
#pragma unroll
    for (int jj = 0; jj < 4; ++jj) {
      float s = 0.f;
      bf16x8 p;
#pragma unroll
      for (int r = 0; r < 4; ++r) {
        const unsigned short u0 = f2bf(__expf(acc[0][jj][r] + bk[jj]));
        const unsigned short u1 = f2bf(__expf(acc[1][jj][r] + bk[jj]));
        p[r] = (short)u0; p[r + 4] = (short)u1;
        s += bf2f(u0) + bf2f(u1);
      }
      pk[jj] = p;
      srow[jj] += s;
    }

    // V phase
#pragma unroll
    for (int a = 0; a < 2; ++a)
#pragma unroll
      for (int b = 0; b < 4; ++b) acc[a][b] = fz;
#pragma unroll
    for (int ks = 0; ks < 8; ++ks) {
      const bf16x8 xa0 = *(const bf16x8*)(xnf + (((size_t)(nr0 + 0) * 8 + ks) * 64 + l) * 8);
      const bf16x8 xa1 = *(const bf16x8*)(xnf + (((size_t)(nr0 + 1) * 8 + ks) * 64 + l) * 8);
#pragma unroll
      for (int jj = 0; jj < 4; ++jj) {
        const bf16x8 bw = *(const bf16x8*)(lds + (((1 * 8 + ks) * 8 + hl * 4 + jj) * 64 + l) * 16);
        acc[0][jj] = __builtin_amdgcn_mfma_f32_16x16x32_bf16(xa0, bw, acc[0][jj], 0, 0, 0);
        acc[1][jj] = __builtin_amdgcn_mfma_f32_16x16x32_bf16(xa1, bw, acc[1][jj], 0, 0, 0);
      }
    }
    bf16x8 pv[4];
#pragma unroll
    for (int jj = 0; jj < 4; ++jj) {
      bf16x8 p;
#pragma unroll
      for (int r = 0; r < 4; ++r) {
        p[r]     = (short)f2bf(acc[0][jj][r] + bv[jj]);
        p[r + 4] = (short)f2bf(acc[1][jj][r] + bv[jj]);
      }
      pv[jj] = p;
    }

    // context accumulate (k-slot bijection identical on pk/pv)
#pragma unroll
    for (int ja = 0; ja < 4; ++ja)
#pragma unroll
      for (int jb = 0; jb < 4; ++jb)
        ctxa[ja][jb] = __builtin_amdgcn_mfma_f32_16x16x32_bf16(pk[ja], pv[jb], ctxa[ja][jb], 0, 0, 0);
  }

  // ---- block-level reduction ----
  __syncthreads();                 // all waves done reading wfrag LDS
  {
    float* dw = (float*)lds + w * 4096 + l * 4;
#pragma unroll
    for (int ja = 0; ja < 4; ++ja)
#pragma unroll
      for (int jb = 0; jb < 4; ++jb)
        *(f32x4*)(dw + (ja * 4 + jb) * 256) = ctxa[ja][jb];
  }
  {
    float* srl = (float*)(lds + 131072);
#pragma unroll
    for (int jj = 0; jj < 4; ++jj) {
      float s = srow[jj];
      s += __shfl_xor(s, 16, 64);
      s += __shfl_xor(s, 32, 64);
      if (l < 16) srl[w * 64 + jj * 16 + q] = s;
    }
  }
  __syncthreads();
  {
    const float* dump = (const float*)lds;
#pragma unroll
    for (int j = 0; j < 4; ++j) {
      const int m4 = j * 512 + t;            // 0..2048 f32x4 outputs
      const int hh = m4 >> 10, p4 = m4 & 1023;
      f32x4 s = *(const f32x4*)(dump + ((hh * 4 + 0) * 4096) + p4 * 4)
              + *(const f32x4*)(dump + ((hh * 4 + 1) * 4096) + p4 * 4)
              + *(const f32x4*)(dump + ((hh * 4 + 2) * 4096) + p4 * 4)
              + *(const f32x4*)(dump + ((hh * 4 + 3) * 4096) + p4 * 4);
      *(f32x4*)(ctxp + (((size_t)(grp * 2 + hh) * 64 + chunk) * 1024 + p4) * 4) = s;
    }
    if (t < 128) {
      const float* srl = (const float*)(lds + 131072);
      const int hh = t >> 6, d = t & 63;
      float s = srl[(hh * 4 + 0) * 64 + d] + srl[(hh * 4 + 1) * 64 + d]
              + srl[(hh * 4 + 2) * 64 + d] + srl[(hh * 4 + 3) * 64 + d];
      sump[((size_t)(grp * 2 + hh) * 64 + d) * 64 + chunk] = s;
    }
  }
}

// ---------------- reduce partials over 64 chunks ----------------
__global__ void k_ctxred(const float* __restrict__ ctxp, const float* __restrict__ sump,
                         float* __restrict__ ctx, float* __restrict__ sexp) {
  const int t = threadIdx.x;
  if (blockIdx.x < 64) {
    const int m4 = blockIdx.x * 128 + t;     // 0..8192
    const int h = m4 >> 10, p4 = m4 & 1023;
    f32x4 s = {0.f, 0.f, 0.f, 0.f};
#pragma unroll 8
    for (int c = 0; c < 64; ++c)
      s += *(const f32x4*)(ctxp + (((size_t)h * 64 + c) * 1024 + p4) * 4);
    const int jajb = p4 >> 6, ll = p4 & 63;
    const int ja = jajb >> 2, jb = jajb & 3;
    const int gg = ll >> 4, qq = ll & 15;
    float* cw = ctx + ((size_t)h * 64 + ja * 16 + gg * 4) * 64 + jb * 16 + qq;
    cw[0] = s[0]; cw[64] = s[1]; cw[128] = s[2]; cw[192] = s[3];
  } else {
    const int r = (blockIdx.x - 64) * 128 + t;
    float s = 0.f;
#pragma unroll 8
    for (int c = 0; c < 64; ++c) s += sump[(size_t)r * 64 + c];
    sexp[r] = s;
  }
}

// ---------------- W2 ----------------
__global__ void k_w2(const float* __restrict__ out_w, const float* __restrict__ ctx,
                     const float* __restrict__ sexp, float* __restrict__ w2) {
  const int r = blockIdx.x;
  const int h = r >> 6, d = r & 63;
  __shared__ float row[64];
  __shared__ float sinv;
  const int t = threadIdx.x;
  if (t < 64) row[t] = ctx[((size_t)h * 64 + d) * 64 + t];
  if (t == 0) sinv = 1.0f / sexp[r];
  __syncthreads();
  float a = 0.f;
  const float* wp = out_w + (size_t)t * 512 + h * 64;
#pragma unroll 8
  for (int e = 0; e < 64; ++e) a += wp[e] * row[e];
  w2[(size_t)t * 512 + r] = a * sinv;
}

// ---------------- Weff = W2 @ Wq ----------------
__global__ void k_weff(const float* __restrict__ w2, const float* __restrict__ qkv_w,
                       float* __restrict__ weff) {
  const int o = blockIdx.x;
  const int c = threadIdx.x;
  __shared__ float row[512];
  row[c] = w2[(size_t)o * 512 + c];
  row[256 + c] = w2[(size_t)o * 512 + 256 + c];
  __syncthreads();
  float a = 0.f;
#pragma unroll 8
  for (int r = 0; r < 512; ++r) a += row[r] * qkv_w[(size_t)r * 256 + c];
  weff[o * 256 + c] = a;
}

// ---------------- Weff -> fragment order ----------------
__global__ void k_wefrag(const float* __restrict__ weff, unsigned short* __restrict__ wf) {
  const int blk = blockIdx.x;
  const int l = threadIdx.x;
  const int row = (blk & 15) * 16 + (l & 15);
  const int c0 = (blk >> 4) * 32 + (l >> 4) * 8;
  const float* src = weff + (size_t)row * 256 + c0;
  union { unsigned short s[8]; u32x4 v; } u;
#pragma unroll
  for (int j = 0; j < 8; ++j) u.s[j] = f2bf(src[j]);
  *(u32x4*)(wf + ((size_t)blk * 64 + l) * 8) = u.v;
}

// ---------------- beff ----------------
__global__ void k_beff(const float* __restrict__ w2, const float* __restrict__ qkv_b,
                       const float* __restrict__ out_b, float* __restrict__ beff) {
  const int o = threadIdx.x;
  float a = out_b[o];
#pragma unroll 8
  for (int r = 0; r < 512; ++r) a += w2[(size_t)o * 512 + r] * qkv_b[r];
  beff[o] = a;
}

// ---------------- final GEMM + coalesced epilogue ----------------
__launch_bounds__(256, 2)
__global__ void k_final(const unsigned short* __restrict__ xn,
                        const unsigned short* __restrict__ wef,
                        const float* __restrict__ beff,
                        float* __restrict__ out) {
  __shared__ unsigned short xlds[32768];   // 64 KB staging, reused for transpose
  const int t = threadIdx.x;
  const int w = t >> 6, l = t & 63;
  const int q = l & 15, g = l >> 4;
  const int si = w >> 1, sj = w & 1;
  const size_t n0 = (size_t)blockIdx.x * 128;
  {
    const u32x4* gs = (const u32x4*)(xn + n0 * 256);
    u32x4* ld = (u32x4*)xlds;
#pragma unroll
    for (int k2 = 0; k2 < 16; ++k2) {
      u32x4 v = __builtin_nontemporal_load(gs + t + 256 * k2);
      ld[t + 256 * k2] = v;
    }
  }
  __syncthreads();
  const f32x4 fz = {0.f, 0.f, 0.f, 0.f};
  f32x4 acc[4][8];
#pragma unroll
  for (int i = 0; i < 4; ++i)
#pragma unroll
    for (int j = 0; j < 8; ++j) acc[i][j] = fz;
#pragma unroll
  for (int ks = 0; ks < 8; ++ks) {
    bf16x8 xa[4];
#pragma unroll
    for (int i = 0; i < 4; ++i) {
      const int nl = si * 64 + i * 16 + q;
      const int boff = nl * 512 + ((ks * 64 + g * 16) ^ ((nl & 7) << 4));
      xa[i] = *(const bf16x8*)((const char*)xlds + boff);
    }
#pragma unroll
    for (int jj = 0; jj < 8; ++jj) {
      const bf16x8 bw = *(const bf16x8*)(wef + (((size_t)(ks * 16 + sj * 8 + jj)) * 64 + l) * 8);
#pragma unroll
      for (int i = 0; i < 4; ++i)
        acc[i][jj] = __builtin_amdgcn_mfma_f32_16x16x32_bf16(xa[i], bw, acc[i][jj], 0, 0, 0);
    }
  }
  // transpose epilogue through LDS: 4 rounds of 64 output rows
  __syncthreads();
  float* trf = (float*)xlds;               // [64][129] floats
#pragma unroll
  for (int k4 = 0; k4 < 4; ++k4) {
    if ((k4 >> 1) == sj) {
#pragma unroll
      for (int jj2 = 0; jj2 < 4; ++jj2) {
        const int jj = (k4 & 1) * 4 + jj2;
        const float be = beff[sj * 128 + jj * 16 + q];
#pragma unroll
        for (int i = 0; i < 4; ++i)
#pragma unroll
          for (int r = 0; r < 4; ++r)
            trf[(jj2 * 16 + q) * 129 + si * 64 + i * 16 + g * 4 + r] = acc[i][jj][r] + be;
      }
    }
    __syncthreads();
#pragma unroll
    for (int j = 0; j < 32; ++j) {
      const int mm = j * 256 + t;          // 8192 floats
      const int ol = mm >> 7, cc = mm & 127;
      out[(size_t)(k4 * 64 + ol) * NSP + n0 + cc] = trf[ol * 129 + cc];
    }
    __syncthreads();
  }
}

extern "C" void kernel_launch(void* const* d_in, const int* in_sizes, int n_in,
                              void* d_out, int out_size, void* d_ws, size_t ws_size,
                              hipStream_t stream) {
  const float* x     = (const float*)d_in[0];
  const float* gn_w  = (const float*)d_in[1];
  const float* gn_b  = (const float*)d_in[2];
  const float* qkv_w = (const float*)d_in[3];
  const float* qkv_b = (const float*)d_in[4];
  const float* out_w = (const float*)d_in[5];
  const float* out_b = (const float*)d_in[6];
  char* ws = (char*)d_ws;
  unsigned short* xn  = (unsigned short*)(ws + WS_XN);
  unsigned short* wf  = (unsigned short*)(ws + WS_WFRAG);
  unsigned short* wef = (unsigned short*)(ws + WS_WEFRAG);
  float* part   = (float*)(ws + WS_PART);
  float* ab     = (float*)(ws + WS_AB);
  float* ctx    = (float*)(ws + WS_CTX);
  float* w2     = (float*)(ws + WS_W2);
  float* weff   = (float*)(ws + WS_WEFF);
  float* beff   = (float*)(ws + WS_BEFF);
  float* out    = (float*)d_out;
  // d_out scratch (fully overwritten by k_final):
  unsigned short* xnf = (unsigned short*)d_out;             // 32 MB
  float* ctxp = (float*)((char*)d_out + 33554432ULL);       //  8 MB
  float* sump = (float*)((char*)d_out + 41943040ULL);       // 128 KB

  k_wfrag<<<512, 64, 0, stream>>>(qkv_w, wf);
  k_stats<<<256, 256, 0, stream>>>(x, part);
  k_coef<<<1, 256, 0, stream>>>(part, gn_w, gn_b, ab);
  k_xn<<<dim3(1024, 4), 256, 0, stream>>>(x, ab, xn, xnf);
  k_kvctx<<<256, 512, 0, stream>>>(xnf, wf, qkv_b, sump, ctxp);
  k_ctxred<<<68, 128, 0, stream>>>(ctxp, sump, ctx, part);
  k_w2<<<512, 256, 0, stream>>>(out_w, ctx, part, w2);
  k_weff<<<256, 256, 0, stream>>>(w2, qkv_w, weff);
  k_wefrag<<<128, 64, 0, stream>>>(weff, wef);
  k_beff<<<1, 256, 0, stream>>>(w2, qkv_b, out_b, beff);
  k_final<<<512, 256, 0, stream>>>(xn, wef, beff, out);
}